// Round 2
// baseline (3202.014 us; speedup 1.0000x reference)
//
#include <hip/hip_runtime.h>
#include <math.h>

#define NN 50000
#define NE 800000
#define AD 32
#define ED 16
#define HD 64
#define NG 256

#define SINW 73   // u32 row stride of sIn / sW1T (146 bf16: 144 + pad, odd in words)
#define SHID 67   // fp32 row stride of sHid (odd)

__device__ __forceinline__ float blo(unsigned u){ return __uint_as_float(u << 16); }
__device__ __forceinline__ float bhi(unsigned u){ return __uint_as_float(u & 0xffff0000u); }
__device__ __forceinline__ unsigned short f2bf(float f){
  unsigned u = __float_as_uint(f);
  u += 0x7fffu + ((u >> 16) & 1u);          // round-to-nearest-even
  return (unsigned short)(u >> 16);
}
__device__ __forceinline__ unsigned packbf2(float a, float b){
  return (unsigned)f2bf(a) | ((unsigned)f2bf(b) << 16);
}

// ---------------- embed: h[n][j] = sum_k x[n][k] * We[k][j] + be[j] (pure fp32) ----------------
__global__ __launch_bounds__(256) void k_embed(const float* __restrict__ x,
                                               const float* __restrict__ We,
                                               const float* __restrict__ be,
                                               float* __restrict__ h)
{
  const int t = threadIdx.x;
  const int j = t & 63, nd = t >> 6;
  const int node = blockIdx.x * 4 + nd;
  const float* xr = x + (size_t)node * AD;
  float acc = be[j];
  #pragma unroll 8
  for (int k = 0; k < AD; ++k)
    acc += xr[k] * We[k * HD + j];
  h[(size_t)node * HD + j] = acc;
}

// ---------------- edge MLP + scatter: 64 edges per block ----------------
__global__ __launch_bounds__(256) void k_edge(const float* __restrict__ h,
                                              const int* __restrict__ eidx,
                                              const float* __restrict__ eattr,
                                              const float* __restrict__ W1,
                                              const float* __restrict__ b1,
                                              const float* __restrict__ W2,
                                              const float* __restrict__ b2,
                                              float* __restrict__ agg)
{
  __shared__ unsigned sW1T[64 * SINW];   // W1T[j][k] bf16 pairs
  __shared__ unsigned sIn[64 * SINW];    // in[e][k] bf16 pairs
  __shared__ unsigned sW2T[64 * 33];     // W2T[j][k] bf16 pairs
  __shared__ float    sHid[64 * SHID];   // hidden[e][j] fp32
  __shared__ int      sDst[64];

  const int t = threadIdx.x;

  // ---- stage weights (transposed: row j = column j of W), fp32 -> bf16 ----
  {
    unsigned short* w1s = (unsigned short*)sW1T;
    for (int i = t; i < 144 * 64; i += 256){
      int k = i >> 6, j = i & 63;
      w1s[j * 146 + k] = f2bf(W1[i]);
    }
    unsigned short* w2s = (unsigned short*)sW2T;
    for (int i = t; i < 64 * 64; i += 256){
      int k = i >> 6, j = i & 63;
      w2s[j * 66 + k] = f2bf(W2[i]);
    }
  }

  // ---- stage inputs: 4 threads per edge; in[e] = [h_src(64) | h_dst(64) | attr(16)] ----
  {
    const int le = t >> 2, p = t & 3;
    const int e = blockIdx.x * 64 + le;
    const int src  = eidx[e];
    const int dstn = eidx[NE + e];
    if (p == 0) sDst[le] = dstn;
    const float* hs = h + (size_t)src * HD + p * 16;
    unsigned base = le * SINW + p * 8;
    #pragma unroll
    for (int q = 0; q < 4; ++q){
      float4 v = *(const float4*)(hs + q * 4);
      sIn[base + q * 2 + 0] = packbf2(v.x, v.y);
      sIn[base + q * 2 + 1] = packbf2(v.z, v.w);
    }
    const float* hdp = h + (size_t)dstn * HD + p * 16;
    base = le * SINW + 32 + p * 8;
    #pragma unroll
    for (int q = 0; q < 4; ++q){
      float4 v = *(const float4*)(hdp + q * 4);
      sIn[base + q * 2 + 0] = packbf2(v.x, v.y);
      sIn[base + q * 2 + 1] = packbf2(v.z, v.w);
    }
    if (p < 2){
      const float* ea = eattr + (size_t)e * 16 + p * 8;
      float4 v0 = *(const float4*)(ea);
      float4 v1 = *(const float4*)(ea + 4);
      unsigned b = le * SINW + 64 + p * 4;
      sIn[b + 0] = packbf2(v0.x, v0.y);
      sIn[b + 1] = packbf2(v0.z, v0.w);
      sIn[b + 2] = packbf2(v1.x, v1.y);
      sIn[b + 3] = packbf2(v1.z, v1.w);
    }
  }
  __syncthreads();

  const int eb = (t & 15) << 2;   // 4 edges
  const int jb = (t >> 4) << 2;   // 4 cols

  // ---- hidden = relu(in @ W1 + b1) ----
  float acc[4][4] = {};
  #pragma unroll 4
  for (int kk = 0; kk < 72; ++kk){          // 144 k as 72 bf16-pairs
    unsigned a0 = sIn[(eb + 0) * SINW + kk];
    unsigned a1 = sIn[(eb + 1) * SINW + kk];
    unsigned a2 = sIn[(eb + 2) * SINW + kk];
    unsigned a3 = sIn[(eb + 3) * SINW + kk];
    unsigned w0 = sW1T[(jb + 0) * SINW + kk];
    unsigned w1 = sW1T[(jb + 1) * SINW + kk];
    unsigned w2 = sW1T[(jb + 2) * SINW + kk];
    unsigned w3 = sW1T[(jb + 3) * SINW + kk];
    float al[4][2] = {{blo(a0),bhi(a0)},{blo(a1),bhi(a1)},{blo(a2),bhi(a2)},{blo(a3),bhi(a3)}};
    float wl[4][2] = {{blo(w0),bhi(w0)},{blo(w1),bhi(w1)},{blo(w2),bhi(w2)},{blo(w3),bhi(w3)}};
    #pragma unroll
    for (int ee = 0; ee < 4; ++ee)
      #pragma unroll
      for (int jj = 0; jj < 4; ++jj)
        acc[ee][jj] += al[ee][0] * wl[jj][0] + al[ee][1] * wl[jj][1];
  }
  #pragma unroll
  for (int jj = 0; jj < 4; ++jj){
    float bv = b1[jb + jj];
    #pragma unroll
    for (int ee = 0; ee < 4; ++ee)
      sHid[(eb + ee) * SHID + jb + jj] = fmaxf(acc[ee][jj] + bv, 0.f);
  }
  __syncthreads();

  // ---- out = hidden @ W2 + b2, atomic scatter to agg[dst] ----
  float occ[4][4] = {};
  #pragma unroll 4
  for (int kk = 0; kk < 32; ++kk){          // 64 k as 32 fp32-pairs
    float ax[4], ay[4];
    #pragma unroll
    for (int ee = 0; ee < 4; ++ee){
      ax[ee] = sHid[(eb + ee) * SHID + 2 * kk];
      ay[ee] = sHid[(eb + ee) * SHID + 2 * kk + 1];
    }
    unsigned w0 = sW2T[(jb + 0) * 33 + kk];
    unsigned w1 = sW2T[(jb + 1) * 33 + kk];
    unsigned w2 = sW2T[(jb + 2) * 33 + kk];
    unsigned w3 = sW2T[(jb + 3) * 33 + kk];
    float wl[4][2] = {{blo(w0),bhi(w0)},{blo(w1),bhi(w1)},{blo(w2),bhi(w2)},{blo(w3),bhi(w3)}};
    #pragma unroll
    for (int ee = 0; ee < 4; ++ee)
      #pragma unroll
      for (int jj = 0; jj < 4; ++jj)
        occ[ee][jj] += ax[ee] * wl[jj][0] + ay[ee] * wl[jj][1];
  }
  int dn[4];
  #pragma unroll
  for (int ee = 0; ee < 4; ++ee) dn[ee] = sDst[eb + ee];
  #pragma unroll
  for (int jj = 0; jj < 4; ++jj){
    float bv = b2[jb + jj];
    #pragma unroll
    for (int ee = 0; ee < 4; ++ee)
      atomicAdd(&agg[(size_t)dn[ee] * HD + jb + jj], occ[ee][jj] + bv);
  }
}

// ---------------- GRU: h = GRUCell(agg, h), 4 nodes per block ----------------
__global__ __launch_bounds__(256) void k_gru(const float* __restrict__ agg,
                                             float* __restrict__ h,
                                             const float* __restrict__ Wih,
                                             const float* __restrict__ bih,
                                             const float* __restrict__ Whh,
                                             const float* __restrict__ bhh)
{
  __shared__ unsigned sWi[192 * 33];   // row g: 32 bf16-pairs + 1 pad (odd stride)
  __shared__ unsigned sWh[192 * 33];
  __shared__ float sA[4 * 64], sH[4 * 64];
  const int t = threadIdx.x;
  for (int i = t; i < 192 * 32; i += 256){
    int r = i >> 5, c = i & 31;
    float2 wi = *(const float2*)(Wih + r * 64 + 2 * c);
    float2 wh = *(const float2*)(Whh + r * 64 + 2 * c);
    sWi[r * 33 + c] = packbf2(wi.x, wi.y);
    sWh[r * 33 + c] = packbf2(wh.x, wh.y);
  }
  const int nd = t >> 6, j = t & 63;
  const int node = blockIdx.x * 4 + nd;
  sA[nd * 64 + j] = agg[(size_t)node * HD + j];
  sH[nd * 64 + j] = h[(size_t)node * HD + j];
  __syncthreads();

  float gir = bih[j],       ghr = bhh[j];
  float giz = bih[64 + j],  ghz = bhh[64 + j];
  float gin = bih[128 + j], ghn = bhh[128 + j];
  const float2* aR = (const float2*)&sA[nd * 64];
  const float2* hR = (const float2*)&sH[nd * 64];
  #pragma unroll 8
  for (int kk = 0; kk < 32; ++kk){
    float2 av = aR[kk], hv = hR[kk];
    unsigned wir = sWi[j * 33 + kk], wiz = sWi[(64 + j) * 33 + kk], win = sWi[(128 + j) * 33 + kk];
    unsigned whr = sWh[j * 33 + kk], whz = sWh[(64 + j) * 33 + kk], whn = sWh[(128 + j) * 33 + kk];
    gir += blo(wir) * av.x + bhi(wir) * av.y;
    giz += blo(wiz) * av.x + bhi(wiz) * av.y;
    gin += blo(win) * av.x + bhi(win) * av.y;
    ghr += blo(whr) * hv.x + bhi(whr) * hv.y;
    ghz += blo(whz) * hv.x + bhi(whz) * hv.y;
    ghn += blo(whn) * hv.x + bhi(whn) * hv.y;
  }
  float r = 1.f / (1.f + __expf(-(gir + ghr)));
  float z = 1.f / (1.f + __expf(-(giz + ghz)));
  float n = tanhf(gin + r * ghn);
  float hold = sH[nd * 64 + j];
  h[(size_t)node * HD + j] = (1.f - z) * n + z * hold;
}

// ---------------- pooled readout: run-length segment sum (batch sorted) ----------------
__global__ __launch_bounds__(256) void k_pool(const float* __restrict__ h,
                                              const int* __restrict__ batch,
                                              float* __restrict__ gsum,
                                              float* __restrict__ cnt)
{
  const int t = threadIdx.x;
  const int j = t & 63, r = t >> 6;
  const int n0 = blockIdx.x * 64 + r * 16;
  float acc = 0.f, c = 0.f;
  int cur = -1;
  for (int i = 0; i < 16; ++i){
    int n = n0 + i;
    if (n >= NN) break;
    int g = batch[n];
    if (g != cur){
      if (cur >= 0){
        atomicAdd(&gsum[cur * HD + j], acc);
        if (j == 0) atomicAdd(&cnt[cur], c);
      }
      cur = g; acc = 0.f; c = 0.f;
    }
    acc += h[(size_t)n * HD + j];
    c += 1.f;
  }
  if (cur >= 0){
    atomicAdd(&gsum[cur * HD + j], acc);
    if (j == 0) atomicAdd(&cnt[cur], c);
  }
}

// ---------------- head: relu([gsum, gmean] @ Wh1 + b1) @ Wh2 + b2 (pure fp32) ----------------
__global__ __launch_bounds__(64) void k_head(const float* __restrict__ gsum,
                                             const float* __restrict__ cnt,
                                             const float* __restrict__ W1,
                                             const float* __restrict__ b1,
                                             const float* __restrict__ W2,
                                             const float* __restrict__ b2,
                                             float* __restrict__ out)
{
  __shared__ float gv[128];
  const int g = blockIdx.x, j = threadIdx.x;
  float s = gsum[g * HD + j];
  float c = cnt[g];
  gv[j] = s;
  gv[64 + j] = s / fmaxf(c, 1.f);
  __syncthreads();
  float acc = b1[j];
  #pragma unroll 8
  for (int k = 0; k < 128; ++k)
    acc += gv[k] * W1[k * HD + j];
  acc = fmaxf(acc, 0.f);
  float v = acc * W2[j];
  #pragma unroll
  for (int off = 32; off; off >>= 1) v += __shfl_down(v, off, 64);
  if (j == 0) out[g] = v + b2[0];
}

extern "C" void kernel_launch(void* const* d_in, const int* in_sizes, int n_in,
                              void* d_out, int out_size, void* d_ws, size_t ws_size,
                              hipStream_t stream)
{
  (void)in_sizes; (void)n_in; (void)out_size; (void)ws_size;
  const float* x     = (const float*)d_in[0];
  const int*   eidx  = (const int*)d_in[1];
  const float* eattr = (const float*)d_in[2];
  const int*   batch = (const int*)d_in[3];
  const float* We    = (const float*)d_in[4];
  const float* be    = (const float*)d_in[5];
  const float* Wm1   = (const float*)d_in[6];
  const float* bm1   = (const float*)d_in[7];
  const float* Wm2   = (const float*)d_in[8];
  const float* bm2   = (const float*)d_in[9];
  const float* Wih   = (const float*)d_in[10];
  const float* bih   = (const float*)d_in[11];
  const float* Whh   = (const float*)d_in[12];
  const float* bhh   = (const float*)d_in[13];
  const float* Wh1   = (const float*)d_in[14];
  const float* bh1   = (const float*)d_in[15];
  const float* Wh2   = (const float*)d_in[16];
  const float* bh2   = (const float*)d_in[17];

  float* h    = (float*)d_ws;
  float* agg  = h + (size_t)NN * HD;
  float* gsum = agg + (size_t)NN * HD;
  float* cnt  = gsum + (size_t)NG * HD;

  k_embed<<<NN / 4, 256, 0, stream>>>(x, We, be, h);
  for (int s = 0; s < 3; ++s){
    hipMemsetAsync(agg, 0, (size_t)NN * HD * sizeof(float), stream);
    k_edge<<<NE / 64, 256, 0, stream>>>(h, eidx, eattr, Wm1, bm1, Wm2, bm2, agg);
    k_gru<<<NN / 4, 256, 0, stream>>>(agg, h, Wih, bih, Whh, bhh);
  }
  hipMemsetAsync(gsum, 0, (size_t)(NG * HD + NG) * sizeof(float), stream);
  k_pool<<<(NN + 63) / 64, 256, 0, stream>>>(h, batch, gsum, cnt);
  k_head<<<NG, 64, 0, stream>>>(gsum, cnt, Wh1, bh1, Wh2, bh2, (float*)d_out);
}

// Round 3
// 1104.523 us; speedup vs baseline: 2.8990x; 2.8990x over previous
//
#include <hip/hip_runtime.h>
#include <math.h>

#define NN 50000
#define NE 800000
#define AD 32
#define ED 16
#define HD 64
#define NG 256

typedef short bf16x8 __attribute__((ext_vector_type(8)));
typedef float f32x4  __attribute__((ext_vector_type(4)));

__device__ __forceinline__ float b2f(unsigned short s){ return __uint_as_float(((unsigned)s) << 16); }
__device__ __forceinline__ float blo(unsigned u){ return __uint_as_float(u << 16); }
__device__ __forceinline__ float bhi(unsigned u){ return __uint_as_float(u & 0xffff0000u); }
__device__ __forceinline__ unsigned short f2bf(float f){
  unsigned u = __float_as_uint(f);
  u += 0x7fffu + ((u >> 16) & 1u);          // RNE
  return (unsigned short)(u >> 16);
}
__device__ __forceinline__ unsigned packbf2(float a, float b){
  return (unsigned)f2bf(a) | ((unsigned)f2bf(b) << 16);
}

// =============== one-time prep: transpose+pad weights to bf16 ===============
// W1Tp[n][k] 64x168 (k<144 real, else 0); W2Tp[n][k] 64x72 (k<64 real);
// Wihp/Whhp: 192x32 u32 of packed bf16 pairs.
__global__ __launch_bounds__(256) void k_prep(const float* __restrict__ W1,
                                              const float* __restrict__ W2,
                                              const float* __restrict__ Wih,
                                              const float* __restrict__ Whh,
                                              unsigned short* __restrict__ W1Tp,
                                              unsigned short* __restrict__ W2Tp,
                                              unsigned* __restrict__ Wihp,
                                              unsigned* __restrict__ Whhp)
{
  int idx = blockIdx.x * 256 + threadIdx.x;
  if (idx < 64 * 168){
    int n = idx / 168, k = idx % 168;
    W1Tp[idx] = (k < 144) ? f2bf(W1[k * 64 + n]) : (unsigned short)0;
    return;
  }
  idx -= 64 * 168;
  if (idx < 64 * 72){
    int n = idx / 72, k = idx % 72;
    W2Tp[idx] = (k < 64) ? f2bf(W2[k * 64 + n]) : (unsigned short)0;
    return;
  }
  idx -= 64 * 72;
  if (idx < 192 * 32){
    int r = idx / 32, c = idx % 32;
    Wihp[idx] = packbf2(Wih[r * 64 + 2 * c], Wih[r * 64 + 2 * c + 1]);
    return;
  }
  idx -= 192 * 32;
  if (idx < 192 * 32){
    int r = idx / 32, c = idx % 32;
    Whhp[idx] = packbf2(Whh[r * 64 + 2 * c], Whh[r * 64 + 2 * c + 1]);
  }
}

// =============== CSR build ===============
__global__ __launch_bounds__(256) void k_hist(const int* __restrict__ eidx, int* __restrict__ deg)
{
  int e = blockIdx.x * 256 + threadIdx.x;
  if (e < NE) atomicAdd(&deg[eidx[NE + e]], 1);
}

__global__ __launch_bounds__(1024) void k_scan(const int* __restrict__ deg,
                                               int* __restrict__ off,
                                               int* __restrict__ cur)
{
  __shared__ int s[1024];
  __shared__ int sCarry;
  const int t = threadIdx.x;
  if (t == 0) sCarry = 0;
  __syncthreads();
  for (int b = 0; b < NN; b += 8192){
    int v[8]; int tot = 0;
    #pragma unroll
    for (int i = 0; i < 8; ++i){
      int idx = b + t * 8 + i;
      v[i] = (idx < NN) ? deg[idx] : 0;
      tot += v[i];
    }
    s[t] = tot;
    __syncthreads();
    for (int d = 1; d < 1024; d <<= 1){
      int y = (t >= d) ? s[t - d] : 0;
      __syncthreads();
      s[t] += y;
      __syncthreads();
    }
    int run = s[t] - tot + sCarry;     // exclusive prefix for this thread's 8
    #pragma unroll
    for (int i = 0; i < 8; ++i){
      int idx = b + t * 8 + i;
      if (idx < NN){ off[idx] = run; cur[idx] = run; }
      run += v[i];
    }
    __syncthreads();
    if (t == 1023) sCarry += s[1023];
    __syncthreads();
  }
  if (t == 0) off[NN] = sCarry;
}

__global__ __launch_bounds__(256) void k_scatter(const int* __restrict__ eidx,
                                                 int* __restrict__ cur,
                                                 int* __restrict__ perm)
{
  int e = blockIdx.x * 256 + threadIdx.x;
  if (e < NE){
    int d = eidx[NE + e];
    int p = atomicAdd(&cur[d], 1);
    perm[p] = e;
  }
}

// =============== embed ===============
__global__ __launch_bounds__(256) void k_embed(const float* __restrict__ x,
                                               const float* __restrict__ We,
                                               const float* __restrict__ be,
                                               float* __restrict__ h)
{
  const int t = threadIdx.x;
  const int j = t & 63, nd = t >> 6;
  const int node = blockIdx.x * 4 + nd;
  const float* xr = x + (size_t)node * AD;
  float acc = be[j];
  #pragma unroll 8
  for (int k = 0; k < AD; ++k)
    acc += xr[k] * We[k * HD + j];
  h[(size_t)node * HD + j] = acc;
}

// =============== edge MLP (MFMA) + in-block segment reduce ===============
// 64 dst-sorted edges per block, 4 waves, 16 edges per wave.
__global__ __launch_bounds__(256) void k_edge(const float* __restrict__ h,
                                              const int* __restrict__ eidx,
                                              const float* __restrict__ eattr,
                                              const unsigned short* __restrict__ W1Tp,
                                              const float* __restrict__ b1,
                                              const unsigned short* __restrict__ W2Tp,
                                              const float* __restrict__ b2,
                                              const int* __restrict__ perm,
                                              float* __restrict__ agg)
{
  __shared__ __align__(16) unsigned short sW1T[64 * 168];
  __shared__ __align__(16) unsigned short sIn [64 * 168];   // later reused as sOut (64x72)
  __shared__ __align__(16) unsigned short sW2T[64 * 72];
  __shared__ __align__(16) unsigned short sHid[64 * 72];
  __shared__ int sDst[64];
  __shared__ int sRunPos[65];
  __shared__ int sRunDst[64];
  __shared__ int sNR;

  const int t = threadIdx.x;
  const int base = blockIdx.x * 64;

  // ---- stage weights (already transposed+packed bf16 in global) ----
  {
    const unsigned* w1 = (const unsigned*)W1Tp;
    unsigned* d1 = (unsigned*)sW1T;
    for (int i = t; i < 64 * 168 / 2; i += 256) d1[i] = w1[i];
    const unsigned* w2 = (const unsigned*)W2Tp;
    unsigned* d2 = (unsigned*)sW2T;
    for (int i = t; i < 64 * 72 / 2; i += 256) d2[i] = w2[i];
  }

  // ---- stage inputs: 4 threads/edge; in[e] = [h_src | h_dst | attr | 0-pad] bf16 ----
  {
    const int le = t >> 2, p = t & 3;
    const int e = perm[base + le];
    const int src  = eidx[e];
    const int dstn = eidx[NE + e];
    if (p == 0) sDst[le] = dstn;
    unsigned* row = (unsigned*)&sIn[le * 168];
    const float* hs = h + (size_t)src * HD + p * 16;
    #pragma unroll
    for (int q = 0; q < 4; ++q){
      float4 v = *(const float4*)(hs + q * 4);
      row[p * 8 + q * 2 + 0] = packbf2(v.x, v.y);
      row[p * 8 + q * 2 + 1] = packbf2(v.z, v.w);
    }
    const float* hd = h + (size_t)dstn * HD + p * 16;
    #pragma unroll
    for (int q = 0; q < 4; ++q){
      float4 v = *(const float4*)(hd + q * 4);
      row[32 + p * 8 + q * 2 + 0] = packbf2(v.x, v.y);
      row[32 + p * 8 + q * 2 + 1] = packbf2(v.z, v.w);
    }
    if (p < 2){
      const float* ea = eattr + (size_t)e * 16 + p * 8;
      float4 v0 = *(const float4*)(ea);
      float4 v1 = *(const float4*)(ea + 4);
      row[64 + p * 4 + 0] = packbf2(v0.x, v0.y);
      row[64 + p * 4 + 1] = packbf2(v0.z, v0.w);
      row[64 + p * 4 + 2] = packbf2(v1.x, v1.y);
      row[64 + p * 4 + 3] = packbf2(v1.z, v1.w);
    } else {
      // zero pad k = 144..159  (u32 words 72..79)
      row[72 + (p - 2) * 4 + 0] = 0;
      row[72 + (p - 2) * 4 + 1] = 0;
      row[72 + (p - 2) * 4 + 2] = 0;
      row[72 + (p - 2) * 4 + 3] = 0;
    }
  }
  __syncthreads();

  // ---- run detection over sorted dsts (wave 0) ----
  if (t < 64){
    bool isStart = (t == 0) || (sDst[t] != sDst[t - 1]);
    unsigned long long m = __ballot(isStart);
    if (isStart){
      int r = (t == 0) ? 0 : __popcll(m & ((1ULL << t) - 1ULL));
      sRunPos[r] = t; sRunDst[r] = sDst[t];
    }
    if (t == 0){ int nr = __popcll(m); sNR = nr; sRunPos[nr] = 64; }
  }

  const int lane = t & 63, wv = t >> 6;
  const int mrow = lane & 15, q = lane >> 4;

  // ---- GEMM1: hidden = relu(in @ W1 + b1), K=160(padded), 4 n-tiles ----
  f32x4 a0 = {0.f,0.f,0.f,0.f}, a1 = a0, a2 = a0, a3 = a0;
  const unsigned short* aBase = &sIn[(wv * 16 + mrow) * 168 + q * 8];
  #pragma unroll
  for (int ks = 0; ks < 5; ++ks){
    bf16x8 av = *(const bf16x8*)(aBase + ks * 32);
    bf16x8 b0v = *(const bf16x8*)&sW1T[( 0 + mrow) * 168 + ks * 32 + q * 8];
    bf16x8 b1v = *(const bf16x8*)&sW1T[(16 + mrow) * 168 + ks * 32 + q * 8];
    bf16x8 b2v = *(const bf16x8*)&sW1T[(32 + mrow) * 168 + ks * 32 + q * 8];
    bf16x8 b3v = *(const bf16x8*)&sW1T[(48 + mrow) * 168 + ks * 32 + q * 8];
    a0 = __builtin_amdgcn_mfma_f32_16x16x32_bf16(av, b0v, a0, 0, 0, 0);
    a1 = __builtin_amdgcn_mfma_f32_16x16x32_bf16(av, b1v, a1, 0, 0, 0);
    a2 = __builtin_amdgcn_mfma_f32_16x16x32_bf16(av, b2v, a2, 0, 0, 0);
    a3 = __builtin_amdgcn_mfma_f32_16x16x32_bf16(av, b3v, a3, 0, 0, 0);
  }
  // bias + relu -> sHid bf16   (C layout: col=lane&15, row=q*4+reg)
  {
    f32x4 accs[4] = {a0, a1, a2, a3};
    #pragma unroll
    for (int tl = 0; tl < 4; ++tl){
      float bv = b1[tl * 16 + mrow];
      #pragma unroll
      for (int r = 0; r < 4; ++r){
        float vv = fmaxf(accs[tl][r] + bv, 0.f);
        sHid[(wv * 16 + q * 4 + r) * 72 + tl * 16 + mrow] = f2bf(vv);
      }
    }
  }
  __syncthreads();

  // ---- GEMM2: out = hidden @ W2 + b2, K=64 ----
  f32x4 o0 = {0.f,0.f,0.f,0.f}, o1 = o0, o2 = o0, o3 = o0;
  const unsigned short* hBase = &sHid[(wv * 16 + mrow) * 72 + q * 8];
  #pragma unroll
  for (int ks = 0; ks < 2; ++ks){
    bf16x8 av = *(const bf16x8*)(hBase + ks * 32);
    bf16x8 b0v = *(const bf16x8*)&sW2T[( 0 + mrow) * 72 + ks * 32 + q * 8];
    bf16x8 b1v = *(const bf16x8*)&sW2T[(16 + mrow) * 72 + ks * 32 + q * 8];
    bf16x8 b2v = *(const bf16x8*)&sW2T[(32 + mrow) * 72 + ks * 32 + q * 8];
    bf16x8 b3v = *(const bf16x8*)&sW2T[(48 + mrow) * 72 + ks * 32 + q * 8];
    o0 = __builtin_amdgcn_mfma_f32_16x16x32_bf16(av, b0v, o0, 0, 0, 0);
    o1 = __builtin_amdgcn_mfma_f32_16x16x32_bf16(av, b1v, o1, 0, 0, 0);
    o2 = __builtin_amdgcn_mfma_f32_16x16x32_bf16(av, b2v, o2, 0, 0, 0);
    o3 = __builtin_amdgcn_mfma_f32_16x16x32_bf16(av, b3v, o3, 0, 0, 0);
  }
  // + b2 -> sOut (reuse sIn region, stride 72)
  unsigned short* sOut = sIn;
  {
    f32x4 outs[4] = {o0, o1, o2, o3};
    #pragma unroll
    for (int tl = 0; tl < 4; ++tl){
      float bv = b2[tl * 16 + mrow];
      #pragma unroll
      for (int r = 0; r < 4; ++r)
        sOut[(wv * 16 + q * 4 + r) * 72 + tl * 16 + mrow] = f2bf(outs[tl][r] + bv);
    }
  }
  __syncthreads();

  // ---- segment reduce per dst-run; plain store for interior runs ----
  {
    const int j = t & 63, qt = t >> 6;
    const int nr = sNR;
    for (int r = qt; r < nr; r += 4){
      int lo = sRunPos[r], hi = sRunPos[r + 1];
      float s = 0.f;
      for (int m = lo; m < hi; ++m)
        s += b2f(sOut[m * 72 + j]);
      float* dp = &agg[(size_t)sRunDst[r] * HD + j];
      if (r == 0 || r == nr - 1) atomicAdd(dp, s);
      else *dp = s;
    }
  }
}

// =============== GRU: 16 nodes per block ===============
__global__ __launch_bounds__(256) void k_gru(const float* __restrict__ agg,
                                             float* __restrict__ h,
                                             const unsigned* __restrict__ Wihp,
                                             const float* __restrict__ bih,
                                             const unsigned* __restrict__ Whhp,
                                             const float* __restrict__ bhh)
{
  __shared__ unsigned sWi[192 * 33];
  __shared__ unsigned sWh[192 * 33];
  __shared__ float sA[16 * 64], sH[16 * 64];
  const int t = threadIdx.x;
  for (int i = t; i < 192 * 32; i += 256){
    int r = i >> 5, c = i & 31;
    sWi[r * 33 + c] = Wihp[i];
    sWh[r * 33 + c] = Whhp[i];
  }
  const int j = t & 63, nd0 = t >> 6;
  const int nb = blockIdx.x * 16;
  for (int ln = nd0; ln < 16; ln += 4){
    sA[ln * 64 + j] = agg[(size_t)(nb + ln) * HD + j];
    sH[ln * 64 + j] = h[(size_t)(nb + ln) * HD + j];
  }
  __syncthreads();
  const float bir = bih[j], biz = bih[64 + j], bin_ = bih[128 + j];
  const float bhr = bhh[j], bhz = bhh[64 + j], bhn  = bhh[128 + j];
  for (int ln = nd0; ln < 16; ln += 4){
    float gir = bir, ghr = bhr, giz = biz, ghz = bhz, gin = bin_, ghn = bhn;
    const float2* aR = (const float2*)&sA[ln * 64];
    const float2* hR = (const float2*)&sH[ln * 64];
    #pragma unroll 8
    for (int kk = 0; kk < 32; ++kk){
      float2 av = aR[kk], hv = hR[kk];
      unsigned wir = sWi[j * 33 + kk], wiz = sWi[(64 + j) * 33 + kk], win = sWi[(128 + j) * 33 + kk];
      unsigned whr = sWh[j * 33 + kk], whz = sWh[(64 + j) * 33 + kk], whn = sWh[(128 + j) * 33 + kk];
      gir += blo(wir) * av.x + bhi(wir) * av.y;
      giz += blo(wiz) * av.x + bhi(wiz) * av.y;
      gin += blo(win) * av.x + bhi(win) * av.y;
      ghr += blo(whr) * hv.x + bhi(whr) * hv.y;
      ghz += blo(whz) * hv.x + bhi(whz) * hv.y;
      ghn += blo(whn) * hv.x + bhi(whn) * hv.y;
    }
    float r = 1.f / (1.f + __expf(-(gir + ghr)));
    float z = 1.f / (1.f + __expf(-(giz + ghz)));
    float n = tanhf(gin + r * ghn);
    float hold = sH[ln * 64 + j];
    h[(size_t)(nb + ln) * HD + j] = (1.f - z) * n + z * hold;
  }
}

// =============== pool ===============
__global__ __launch_bounds__(256) void k_pool(const float* __restrict__ h,
                                              const int* __restrict__ batch,
                                              float* __restrict__ gsum,
                                              float* __restrict__ cnt)
{
  const int t = threadIdx.x;
  const int j = t & 63, r = t >> 6;
  const int n0 = blockIdx.x * 64 + r * 16;
  float acc = 0.f, c = 0.f;
  int cur = -1;
  for (int i = 0; i < 16; ++i){
    int n = n0 + i;
    if (n >= NN) break;
    int g = batch[n];
    if (g != cur){
      if (cur >= 0){
        atomicAdd(&gsum[cur * HD + j], acc);
        if (j == 0) atomicAdd(&cnt[cur], c);
      }
      cur = g; acc = 0.f; c = 0.f;
    }
    acc += h[(size_t)n * HD + j];
    c += 1.f;
  }
  if (cur >= 0){
    atomicAdd(&gsum[cur * HD + j], acc);
    if (j == 0) atomicAdd(&cnt[cur], c);
  }
}

// =============== head ===============
__global__ __launch_bounds__(64) void k_head(const float* __restrict__ gsum,
                                             const float* __restrict__ cnt,
                                             const float* __restrict__ W1,
                                             const float* __restrict__ b1,
                                             const float* __restrict__ W2,
                                             const float* __restrict__ b2,
                                             float* __restrict__ out)
{
  __shared__ float gv[128];
  const int g = blockIdx.x, j = threadIdx.x;
  float s = gsum[g * HD + j];
  float c = cnt[g];
  gv[j] = s;
  gv[64 + j] = s / fmaxf(c, 1.f);
  __syncthreads();
  float acc = b1[j];
  #pragma unroll 8
  for (int k = 0; k < 128; ++k)
    acc += gv[k] * W1[k * HD + j];
  acc = fmaxf(acc, 0.f);
  float v = acc * W2[j];
  #pragma unroll
  for (int off = 32; off; off >>= 1) v += __shfl_down(v, off, 64);
  if (j == 0) out[g] = v + b2[0];
}

extern "C" void kernel_launch(void* const* d_in, const int* in_sizes, int n_in,
                              void* d_out, int out_size, void* d_ws, size_t ws_size,
                              hipStream_t stream)
{
  (void)in_sizes; (void)n_in; (void)out_size; (void)ws_size;
  const float* x     = (const float*)d_in[0];
  const int*   eidx  = (const int*)d_in[1];
  const float* eattr = (const float*)d_in[2];
  const int*   batch = (const int*)d_in[3];
  const float* We    = (const float*)d_in[4];
  const float* be    = (const float*)d_in[5];
  const float* Wm1   = (const float*)d_in[6];
  const float* bm1   = (const float*)d_in[7];
  const float* Wm2   = (const float*)d_in[8];
  const float* bm2   = (const float*)d_in[9];
  const float* Wih   = (const float*)d_in[10];
  const float* bih   = (const float*)d_in[11];
  const float* Whh   = (const float*)d_in[12];
  const float* bhh   = (const float*)d_in[13];
  const float* Wh1   = (const float*)d_in[14];
  const float* bh1   = (const float*)d_in[15];
  const float* Wh2   = (const float*)d_in[16];
  const float* bh2   = (const float*)d_in[17];

  char* w = (char*)d_ws;
  float* h    = (float*)w;                         w += (size_t)NN * HD * 4;
  float* agg  = (float*)w;                         w += (size_t)NN * HD * 4;
  int*   deg  = (int*)w;                           w += (size_t)NN * 4;
  int*   off  = (int*)w;                           w += (size_t)(NN + 1) * 4 + 4;
  int*   cur  = (int*)w;                           w += (size_t)NN * 4;
  int*   perm = (int*)w;                           w += (size_t)NE * 4;
  unsigned short* W1Tp = (unsigned short*)w;       w += 64 * 168 * 2;
  unsigned short* W2Tp = (unsigned short*)w;       w += 64 * 72 * 2;
  unsigned* Wihp = (unsigned*)w;                   w += 192 * 32 * 4;
  unsigned* Whhp = (unsigned*)w;                   w += 192 * 32 * 4;
  float* gsum = (float*)w;                         w += (size_t)NG * HD * 4;
  float* cnt  = (float*)w;                         w += (size_t)NG * 4;

  // one-time per launch: weight prep + CSR build
  k_prep<<<108, 256, 0, stream>>>(Wm1, Wm2, Wih, Whh, W1Tp, W2Tp, Wihp, Whhp);
  hipMemsetAsync(deg, 0, (size_t)NN * 4, stream);
  k_hist<<<(NE + 255) / 256, 256, 0, stream>>>(eidx, deg);
  k_scan<<<1, 1024, 0, stream>>>(deg, off, cur);
  k_scatter<<<(NE + 255) / 256, 256, 0, stream>>>(eidx, cur, perm);

  k_embed<<<NN / 4, 256, 0, stream>>>(x, We, be, h);
  for (int s = 0; s < 3; ++s){
    hipMemsetAsync(agg, 0, (size_t)NN * HD * 4, stream);
    k_edge<<<NE / 64, 256, 0, stream>>>(h, eidx, eattr, W1Tp, bm1, W2Tp, bm2, perm, agg);
    k_gru<<<NN / 16, 256, 0, stream>>>(agg, h, Wihp, bih, Whhp, bhh);
  }
  hipMemsetAsync(gsum, 0, (size_t)(NG * HD + NG) * 4, stream);
  k_pool<<<(NN + 63) / 64, 256, 0, stream>>>(h, batch, gsum, cnt);
  k_head<<<NG, 64, 0, stream>>>(gsum, cnt, Wh1, bh1, Wh2, bh2, (float*)d_out);
}

// Round 4
// 1103.398 us; speedup vs baseline: 2.9020x; 1.0010x over previous
//
#include <hip/hip_runtime.h>
#include <math.h>

#define NN 50000
#define NE 800000
#define AD 32
#define ED 16
#define HD 64
#define NG 256
#define NTILES (NE / 16)   // 50000 wave-tiles of 16 edges
#define EGRID 1024         // persistent blocks for k_edge

typedef short bf16x8 __attribute__((ext_vector_type(8)));
typedef float f32x4  __attribute__((ext_vector_type(4)));
union U4B { uint4 u; bf16x8 v; };

__device__ __forceinline__ float b2f(unsigned short s){ return __uint_as_float(((unsigned)s) << 16); }
__device__ __forceinline__ float blo(unsigned u){ return __uint_as_float(u << 16); }
__device__ __forceinline__ float bhi(unsigned u){ return __uint_as_float(u & 0xffff0000u); }
__device__ __forceinline__ unsigned short f2bf(float f){
  unsigned u = __float_as_uint(f);
  u += 0x7fffu + ((u >> 16) & 1u);          // RNE
  return (unsigned short)(u >> 16);
}
__device__ __forceinline__ unsigned packbf2(float a, float b){
  return (unsigned)f2bf(a) | ((unsigned)f2bf(b) << 16);
}
__device__ __forceinline__ bf16x8 ldfrag_g(const unsigned* p){
  U4B x; x.u = *(const uint4*)p; return x.v;
}

// =============== one-time prep: transpose+pad weights to bf16 ===============
__global__ __launch_bounds__(256) void k_prep(const float* __restrict__ W1,
                                              const float* __restrict__ W2,
                                              const float* __restrict__ Wih,
                                              const float* __restrict__ Whh,
                                              unsigned short* __restrict__ W1Tp,  // [64][168]
                                              unsigned short* __restrict__ W2Tp,  // [64][72]
                                              unsigned* __restrict__ Wihp,        // [192][32] packed pairs
                                              unsigned* __restrict__ Whhp)
{
  int idx = blockIdx.x * 256 + threadIdx.x;
  if (idx < 64 * 168){
    int n = idx / 168, k = idx % 168;
    W1Tp[idx] = (k < 144) ? f2bf(W1[k * 64 + n]) : (unsigned short)0;
    return;
  }
  idx -= 64 * 168;
  if (idx < 64 * 72){
    int n = idx / 72, k = idx % 72;
    W2Tp[idx] = (k < 64) ? f2bf(W2[k * 64 + n]) : (unsigned short)0;
    return;
  }
  idx -= 64 * 72;
  if (idx < 192 * 32){
    int r = idx / 32, c = idx % 32;
    Wihp[idx] = packbf2(Wih[r * 64 + 2 * c], Wih[r * 64 + 2 * c + 1]);
    return;
  }
  idx -= 192 * 32;
  if (idx < 192 * 32){
    int r = idx / 32, c = idx % 32;
    Whhp[idx] = packbf2(Whh[r * 64 + 2 * c], Whh[r * 64 + 2 * c + 1]);
  }
}

// =============== CSR build ===============
__global__ __launch_bounds__(256) void k_hist(const int* __restrict__ eidx, int* __restrict__ deg)
{
  int e = blockIdx.x * 256 + threadIdx.x;
  if (e < NE) atomicAdd(&deg[eidx[NE + e]], 1);
}

// hierarchical scan: 49 blocks x 1024
__global__ __launch_bounds__(1024) void k_scan1(const int* __restrict__ deg,
                                                int* __restrict__ cur,
                                                int* __restrict__ bsum)
{
  __shared__ int s[1024];
  const int t = threadIdx.x;
  const int idx = blockIdx.x * 1024 + t;
  int v = (idx < NN) ? deg[idx] : 0;
  s[t] = v;
  __syncthreads();
  for (int d = 1; d < 1024; d <<= 1){
    int y = (t >= d) ? s[t - d] : 0;
    __syncthreads();
    s[t] += y;
    __syncthreads();
  }
  if (idx < NN) cur[idx] = s[t] - v;
  if (t == 1023) bsum[blockIdx.x] = s[1023];
}

__global__ __launch_bounds__(64) void k_scan2(const int* __restrict__ bsum,
                                              int* __restrict__ bpre)
{
  const int t = threadIdx.x;
  const int nb = (NN + 1023) / 1024;
  int v = (t < nb) ? bsum[t] : 0;
  int orig = v;
  #pragma unroll
  for (int off = 1; off < 64; off <<= 1){
    int u = __shfl_up(v, off);
    if (t >= off) v += u;
  }
  if (t < nb) bpre[t] = v - orig;
}

__global__ __launch_bounds__(1024) void k_scan3(int* __restrict__ cur,
                                                const int* __restrict__ bpre)
{
  const int idx = blockIdx.x * 1024 + threadIdx.x;
  if (idx < NN) cur[idx] += bpre[blockIdx.x];
}

__global__ __launch_bounds__(256) void k_scatter(const int* __restrict__ eidx,
                                                 int* __restrict__ cur,
                                                 int* __restrict__ perm)
{
  int e = blockIdx.x * 256 + threadIdx.x;
  if (e < NE){
    int d = eidx[NE + e];
    int p = atomicAdd(&cur[d], 1);
    perm[p] = e;
  }
}

// =============== embed: h + h_bf ===============
__global__ __launch_bounds__(256) void k_embed(const float* __restrict__ x,
                                               const float* __restrict__ We,
                                               const float* __restrict__ be,
                                               float* __restrict__ h,
                                               unsigned* __restrict__ h_bf)
{
  const int t = threadIdx.x;
  const int j = t & 63, nd = t >> 6;
  const int node = blockIdx.x * 4 + nd;
  const float* xr = x + (size_t)node * AD;
  float acc = be[j];
  #pragma unroll 8
  for (int k = 0; k < AD; ++k)
    acc += xr[k] * We[k * HD + j];
  h[(size_t)node * HD + j] = acc;
  float p = __shfl_down(acc, 1);
  if (!(j & 1)) h_bf[(size_t)node * 32 + (j >> 1)] = packbf2(acc, p);
}

// =============== edge MLP (MFMA) — per-wave 16-edge tiles, persistent ===============
__global__ __launch_bounds__(256, 4) void k_edge(const unsigned* __restrict__ h_bf,
                                                 const int* __restrict__ eidx,
                                                 const float* __restrict__ eattr,
                                                 const unsigned short* __restrict__ W1Tp,
                                                 const float* __restrict__ b1,
                                                 const unsigned* __restrict__ W2Tp32,
                                                 const float* __restrict__ b2,
                                                 const int* __restrict__ perm,
                                                 float* __restrict__ agg)
{
  __shared__ __align__(16) unsigned short sW1T[64 * 168];
  __shared__ __align__(16) unsigned short sHid[4][16 * 72];   // per-wave; reused for out
  __shared__ int sDst[4][16];

  const int t = threadIdx.x;
  // ---- stage W1T once per block ----
  {
    const uint4* srcp = (const uint4*)W1Tp;
    uint4* dstp = (uint4*)sW1T;
    for (int i = t; i < 64 * 168 * 2 / 16; i += 256) dstp[i] = srcp[i];
  }
  __syncthreads();

  const int lane = t & 63, wv = t >> 6;
  const int m = lane & 15, q = lane >> 4;

  // ---- W2 B-frags in VGPRs (n=lane&15, k=q*8+j) ----
  bf16x8 w2f[4][2];
  #pragma unroll
  for (int tl = 0; tl < 4; ++tl)
    #pragma unroll
    for (int ks = 0; ks < 2; ++ks)
      w2f[tl][ks] = ldfrag_g(W2Tp32 + (tl * 16 + m) * 36 + ks * 16 + q * 4);

  float b1v[4], b2v[4];
  #pragma unroll
  for (int tl = 0; tl < 4; ++tl){ b1v[tl] = b1[tl * 16 + m]; b2v[tl] = b2[tl * 16 + m]; }

  unsigned short* sHidW = sHid[wv];
  int* sDstW = sDst[wv];

  for (int wt = blockIdx.x * 4 + wv; wt < NTILES; wt += EGRID * 4){
    const int base = wt * 16;
    const int e    = perm[base + m];
    const int src  = eidx[e];
    const int dstv = eidx[NE + e];
    if (q == 0) sDstW[m] = dstv;

    // ---- A-frags direct from global (bf16) ----
    bf16x8 af[5];
    const unsigned* hs = h_bf + (size_t)src  * 32;
    const unsigned* hd = h_bf + (size_t)dstv * 32;
    af[0] = ldfrag_g(hs + q * 4);
    af[1] = ldfrag_g(hs + 16 + q * 4);
    af[2] = ldfrag_g(hd + q * 4);
    af[3] = ldfrag_g(hd + 16 + q * 4);
    if (q < 2){
      const float* ea = eattr + (size_t)e * 16 + q * 8;
      float4 v0 = *(const float4*)(ea);
      float4 v1 = *(const float4*)(ea + 4);
      U4B x;
      x.u.x = packbf2(v0.x, v0.y); x.u.y = packbf2(v0.z, v0.w);
      x.u.z = packbf2(v1.x, v1.y); x.u.w = packbf2(v1.z, v1.w);
      af[4] = x.v;
    } else {
      U4B x; x.u = make_uint4(0, 0, 0, 0); af[4] = x.v;
    }

    // ---- GEMM1: hidden = relu(in @ W1 + b1) ----
    f32x4 a0 = {0.f,0.f,0.f,0.f}, a1 = a0, a2 = a0, a3 = a0;
    #pragma unroll
    for (int ks = 0; ks < 5; ++ks){
      bf16x8 bb0 = *(const bf16x8*)&sW1T[( 0 + m) * 168 + ks * 32 + q * 8];
      bf16x8 bb1 = *(const bf16x8*)&sW1T[(16 + m) * 168 + ks * 32 + q * 8];
      bf16x8 bb2 = *(const bf16x8*)&sW1T[(32 + m) * 168 + ks * 32 + q * 8];
      bf16x8 bb3 = *(const bf16x8*)&sW1T[(48 + m) * 168 + ks * 32 + q * 8];
      a0 = __builtin_amdgcn_mfma_f32_16x16x32_bf16(af[ks], bb0, a0, 0, 0, 0);
      a1 = __builtin_amdgcn_mfma_f32_16x16x32_bf16(af[ks], bb1, a1, 0, 0, 0);
      a2 = __builtin_amdgcn_mfma_f32_16x16x32_bf16(af[ks], bb2, a2, 0, 0, 0);
      a3 = __builtin_amdgcn_mfma_f32_16x16x32_bf16(af[ks], bb3, a3, 0, 0, 0);
    }
    {
      f32x4 accs[4] = {a0, a1, a2, a3};
      #pragma unroll
      for (int tl = 0; tl < 4; ++tl)
        #pragma unroll
        for (int r = 0; r < 4; ++r)
          sHidW[(q * 4 + r) * 72 + tl * 16 + m] = f2bf(fmaxf(accs[tl][r] + b1v[tl], 0.f));
    }

    // ---- GEMM2: out = hidden @ W2 + b2 (B from VGPRs) ----
    f32x4 o0 = {0.f,0.f,0.f,0.f}, o1 = o0, o2 = o0, o3 = o0;
    #pragma unroll
    for (int ks = 0; ks < 2; ++ks){
      bf16x8 av = *(const bf16x8*)&sHidW[m * 72 + ks * 32 + q * 8];
      o0 = __builtin_amdgcn_mfma_f32_16x16x32_bf16(av, w2f[0][ks], o0, 0, 0, 0);
      o1 = __builtin_amdgcn_mfma_f32_16x16x32_bf16(av, w2f[1][ks], o1, 0, 0, 0);
      o2 = __builtin_amdgcn_mfma_f32_16x16x32_bf16(av, w2f[2][ks], o2, 0, 0, 0);
      o3 = __builtin_amdgcn_mfma_f32_16x16x32_bf16(av, w2f[3][ks], o3, 0, 0, 0);
    }
    {
      f32x4 outs[4] = {o0, o1, o2, o3};
      #pragma unroll
      for (int tl = 0; tl < 4; ++tl)
        #pragma unroll
        for (int r = 0; r < 4; ++r)
          sHidW[(q * 4 + r) * 72 + tl * 16 + m] = f2bf(outs[tl][r] + b2v[tl]);
    }

    // ---- per-wave segment reduce over 16 sorted edges ----
    int prev = __shfl_up(dstv, 1);
    bool isStart = (m == 0) || (dstv != prev);
    unsigned long long bal = __ballot(isStart);
    unsigned bs = (unsigned)bal & 0xFFFFu;
    int nr = __popc(bs);
    unsigned rem = bs & (bs - 1);   // drop bit 0 (lo starts at 0)
    int lo = 0;
    for (int r = 0; r < nr; ++r){
      int hi = rem ? (__ffs(rem) - 1) : 16;
      rem &= rem - 1;
      float s = 0.f;
      for (int mm = lo; mm < hi; ++mm)
        s += b2f(sHidW[mm * 72 + lane]);
      int d = sDstW[lo];
      float* dp = &agg[(size_t)d * HD + lane];
      if (r == 0 || r == nr - 1) atomicAdd(dp, s);
      else *dp = s;
      lo = hi;
    }
  }
}

// =============== GRU: 16 nodes/block, writes h + h_bf ===============
__global__ __launch_bounds__(256) void k_gru(const float* __restrict__ agg,
                                             float* __restrict__ h,
                                             unsigned* __restrict__ h_bf,
                                             const unsigned* __restrict__ Wihp,
                                             const float* __restrict__ bih,
                                             const unsigned* __restrict__ Whhp,
                                             const float* __restrict__ bhh)
{
  __shared__ unsigned sWi[192 * 33];
  __shared__ unsigned sWh[192 * 33];
  __shared__ float sA[16 * 64], sH[16 * 64];
  const int t = threadIdx.x;
  for (int i = t; i < 192 * 32; i += 256){
    int r = i >> 5, c = i & 31;
    sWi[r * 33 + c] = Wihp[i];
    sWh[r * 33 + c] = Whhp[i];
  }
  const int j = t & 63, nd0 = t >> 6;
  const int nb = blockIdx.x * 16;
  for (int ln = nd0; ln < 16; ln += 4){
    sA[ln * 64 + j] = agg[(size_t)(nb + ln) * HD + j];
    sH[ln * 64 + j] = h[(size_t)(nb + ln) * HD + j];
  }
  __syncthreads();
  const float bir = bih[j], biz = bih[64 + j], bin_ = bih[128 + j];
  const float bhr = bhh[j], bhz = bhh[64 + j], bhn  = bhh[128 + j];
  for (int ln = nd0; ln < 16; ln += 4){
    float gir = bir, ghr = bhr, giz = biz, ghz = bhz, gin = bin_, ghn = bhn;
    const float2* aR = (const float2*)&sA[ln * 64];
    const float2* hR = (const float2*)&sH[ln * 64];
    #pragma unroll 8
    for (int kk = 0; kk < 32; ++kk){
      float2 av = aR[kk], hv = hR[kk];
      unsigned wir = sWi[j * 33 + kk], wiz = sWi[(64 + j) * 33 + kk], win = sWi[(128 + j) * 33 + kk];
      unsigned whr = sWh[j * 33 + kk], whz = sWh[(64 + j) * 33 + kk], whn = sWh[(128 + j) * 33 + kk];
      gir += blo(wir) * av.x + bhi(wir) * av.y;
      giz += blo(wiz) * av.x + bhi(wiz) * av.y;
      gin += blo(win) * av.x + bhi(win) * av.y;
      ghr += blo(whr) * hv.x + bhi(whr) * hv.y;
      ghz += blo(whz) * hv.x + bhi(whz) * hv.y;
      ghn += blo(whn) * hv.x + bhi(whn) * hv.y;
    }
    float r = 1.f / (1.f + __expf(-(gir + ghr)));
    float z = 1.f / (1.f + __expf(-(giz + ghz)));
    float n = tanhf(gin + r * ghn);
    float hold = sH[ln * 64 + j];
    float hnew = (1.f - z) * n + z * hold;
    h[(size_t)(nb + ln) * HD + j] = hnew;
    float p = __shfl_down(hnew, 1);
    if (!(j & 1)) h_bf[(size_t)(nb + ln) * 32 + (j >> 1)] = packbf2(hnew, p);
  }
}

// =============== pool ===============
__global__ __launch_bounds__(256) void k_pool(const float* __restrict__ h,
                                              const int* __restrict__ batch,
                                              float* __restrict__ gsum,
                                              float* __restrict__ cnt)
{
  const int t = threadIdx.x;
  const int j = t & 63, r = t >> 6;
  const int n0 = blockIdx.x * 64 + r * 16;
  float acc = 0.f, c = 0.f;
  int cur = -1;
  for (int i = 0; i < 16; ++i){
    int n = n0 + i;
    if (n >= NN) break;
    int g = batch[n];
    if (g != cur){
      if (cur >= 0){
        atomicAdd(&gsum[cur * HD + j], acc);
        if (j == 0) atomicAdd(&cnt[cur], c);
      }
      cur = g; acc = 0.f; c = 0.f;
    }
    acc += h[(size_t)n * HD + j];
    c += 1.f;
  }
  if (cur >= 0){
    atomicAdd(&gsum[cur * HD + j], acc);
    if (j == 0) atomicAdd(&cnt[cur], c);
  }
}

// =============== head ===============
__global__ __launch_bounds__(64) void k_head(const float* __restrict__ gsum,
                                             const float* __restrict__ cnt,
                                             const float* __restrict__ W1,
                                             const float* __restrict__ b1,
                                             const float* __restrict__ W2,
                                             const float* __restrict__ b2,
                                             float* __restrict__ out)
{
  __shared__ float gv[128];
  const int g = blockIdx.x, j = threadIdx.x;
  float s = gsum[g * HD + j];
  float c = cnt[g];
  gv[j] = s;
  gv[64 + j] = s / fmaxf(c, 1.f);
  __syncthreads();
  float acc = b1[j];
  #pragma unroll 8
  for (int k = 0; k < 128; ++k)
    acc += gv[k] * W1[k * HD + j];
  acc = fmaxf(acc, 0.f);
  float v = acc * W2[j];
  #pragma unroll
  for (int off = 32; off; off >>= 1) v += __shfl_down(v, off, 64);
  if (j == 0) out[g] = v + b2[0];
}

extern "C" void kernel_launch(void* const* d_in, const int* in_sizes, int n_in,
                              void* d_out, int out_size, void* d_ws, size_t ws_size,
                              hipStream_t stream)
{
  (void)in_sizes; (void)n_in; (void)out_size; (void)ws_size;
  const float* x     = (const float*)d_in[0];
  const int*   eidx  = (const int*)d_in[1];
  const float* eattr = (const float*)d_in[2];
  const int*   batch = (const int*)d_in[3];
  const float* We    = (const float*)d_in[4];
  const float* be    = (const float*)d_in[5];
  const float* Wm1   = (const float*)d_in[6];
  const float* bm1   = (const float*)d_in[7];
  const float* Wm2   = (const float*)d_in[8];
  const float* bm2   = (const float*)d_in[9];
  const float* Wih   = (const float*)d_in[10];
  const float* bih   = (const float*)d_in[11];
  const float* Whh   = (const float*)d_in[12];
  const float* bhh   = (const float*)d_in[13];
  const float* Wh1   = (const float*)d_in[14];
  const float* bh1   = (const float*)d_in[15];
  const float* Wh2   = (const float*)d_in[16];
  const float* bh2   = (const float*)d_in[17];

  char* w = (char*)d_ws;
  float* h     = (float*)w;                      w += (size_t)NN * HD * 4;
  unsigned* h_bf = (unsigned*)w;                 w += (size_t)NN * 32 * 4;
  float* agg   = (float*)w;                      w += (size_t)NN * HD * 4;
  int*   deg   = (int*)w;                        w += (size_t)NN * 4;
  int*   cur   = (int*)w;                        w += (size_t)NN * 4;
  int*   perm  = (int*)w;                        w += (size_t)NE * 4;
  int*   bsum  = (int*)w;                        w += 64 * 4;
  int*   bpre  = (int*)w;                        w += 64 * 4;
  unsigned short* W1Tp = (unsigned short*)w;     w += 64 * 168 * 2;
  unsigned short* W2Tp = (unsigned short*)w;     w += 64 * 72 * 2;
  unsigned* Wihp = (unsigned*)w;                 w += 192 * 32 * 4;
  unsigned* Whhp = (unsigned*)w;                 w += 192 * 32 * 4;
  float* gsum  = (float*)w;                      w += (size_t)NG * HD * 4;
  float* cnt   = (float*)w;                      w += (size_t)NG * 4;

  const int nscanb = (NN + 1023) / 1024;

  k_prep<<<108, 256, 0, stream>>>(Wm1, Wm2, Wih, Whh, W1Tp, W2Tp, Wihp, Whhp);
  hipMemsetAsync(deg, 0, (size_t)NN * 4, stream);
  k_hist<<<(NE + 255) / 256, 256, 0, stream>>>(eidx, deg);
  k_scan1<<<nscanb, 1024, 0, stream>>>(deg, cur, bsum);
  k_scan2<<<1, 64, 0, stream>>>(bsum, bpre);
  k_scan3<<<nscanb, 1024, 0, stream>>>(cur, bpre);
  k_scatter<<<(NE + 255) / 256, 256, 0, stream>>>(eidx, cur, perm);

  k_embed<<<NN / 4, 256, 0, stream>>>(x, We, be, h, h_bf);
  for (int s = 0; s < 3; ++s){
    hipMemsetAsync(agg, 0, (size_t)NN * HD * 4, stream);
    k_edge<<<EGRID, 256, 0, stream>>>(h_bf, eidx, eattr, W1Tp, bm1,
                                      (const unsigned*)W2Tp, bm2, perm, agg);
    k_gru<<<NN / 16, 256, 0, stream>>>(agg, h, h_bf, Wihp, bih, Whhp, bhh);
  }
  hipMemsetAsync(gsum, 0, (size_t)(NG * HD + NG) * 4, stream);
  k_pool<<<(NN + 63) / 64, 256, 0, stream>>>(h, batch, gsum, cnt);
  k_head<<<NG, 64, 0, stream>>>(gsum, cnt, Wh1, bh1, Wh2, bh2, (float*)d_out);
}

// Round 5
// 1006.976 us; speedup vs baseline: 3.1798x; 1.0958x over previous
//
#include <hip/hip_runtime.h>
#include <math.h>

#define NN 50000
#define NE 800000
#define AD 32
#define ED 16
#define HD 64
#define NG 256
#define NTILES (NE / 16)     // 50000 wave-tiles of 16 edges
#define EGRID 1024           // persistent blocks for k_edge (128 per XCD)
#define TPX (NTILES / 8)     // tiles per XCD chunk
#define GGRID 512            // persistent blocks for k_gru (2 per CU, LDS-capped)

typedef short bf16x8 __attribute__((ext_vector_type(8)));
typedef float f32x4  __attribute__((ext_vector_type(4)));
union U4B { uint4 u; bf16x8 v; };

__device__ __forceinline__ float b2f(unsigned short s){ return __uint_as_float(((unsigned)s) << 16); }
__device__ __forceinline__ float blo(unsigned u){ return __uint_as_float(u << 16); }
__device__ __forceinline__ float bhi(unsigned u){ return __uint_as_float(u & 0xffff0000u); }
__device__ __forceinline__ unsigned short f2bf(float f){
  unsigned u = __float_as_uint(f);
  u += 0x7fffu + ((u >> 16) & 1u);          // RNE
  return (unsigned short)(u >> 16);
}
__device__ __forceinline__ unsigned packbf2(float a, float b){
  return (unsigned)f2bf(a) | ((unsigned)f2bf(b) << 16);
}
__device__ __forceinline__ bf16x8 ldfrag_g(const unsigned* p){
  U4B x; x.u = *(const uint4*)p; return x.v;
}

// =============== one-time prep: transpose+pad weights to bf16 ===============
__global__ __launch_bounds__(256) void k_prep(const float* __restrict__ W1,
                                              const float* __restrict__ W2,
                                              const float* __restrict__ Wih,
                                              const float* __restrict__ Whh,
                                              unsigned short* __restrict__ W1Tp,  // [64][168]
                                              unsigned short* __restrict__ W2Tp,  // [64][72]
                                              unsigned* __restrict__ Wihp,        // [192][32] packed pairs
                                              unsigned* __restrict__ Whhp)
{
  int idx = blockIdx.x * 256 + threadIdx.x;
  if (idx < 64 * 168){
    int n = idx / 168, k = idx % 168;
    W1Tp[idx] = (k < 144) ? f2bf(W1[k * 64 + n]) : (unsigned short)0;
    return;
  }
  idx -= 64 * 168;
  if (idx < 64 * 72){
    int n = idx / 72, k = idx % 72;
    W2Tp[idx] = (k < 64) ? f2bf(W2[k * 64 + n]) : (unsigned short)0;
    return;
  }
  idx -= 64 * 72;
  if (idx < 192 * 32){
    int r = idx / 32, c = idx % 32;
    Wihp[idx] = packbf2(Wih[r * 64 + 2 * c], Wih[r * 64 + 2 * c + 1]);
    return;
  }
  idx -= 192 * 32;
  if (idx < 192 * 32){
    int r = idx / 32, c = idx % 32;
    Whhp[idx] = packbf2(Whh[r * 64 + 2 * c], Whh[r * 64 + 2 * c + 1]);
  }
}

// =============== CSR build ===============
__global__ __launch_bounds__(256) void k_hist(const int* __restrict__ eidx, int* __restrict__ deg)
{
  int e = blockIdx.x * 256 + threadIdx.x;
  if (e < NE) atomicAdd(&deg[eidx[NE + e]], 1);
}

__global__ __launch_bounds__(1024) void k_scan1(const int* __restrict__ deg,
                                                int* __restrict__ cur,
                                                int* __restrict__ bsum)
{
  __shared__ int s[1024];
  const int t = threadIdx.x;
  const int idx = blockIdx.x * 1024 + t;
  int v = (idx < NN) ? deg[idx] : 0;
  s[t] = v;
  __syncthreads();
  for (int d = 1; d < 1024; d <<= 1){
    int y = (t >= d) ? s[t - d] : 0;
    __syncthreads();
    s[t] += y;
    __syncthreads();
  }
  if (idx < NN) cur[idx] = s[t] - v;
  if (t == 1023) bsum[blockIdx.x] = s[1023];
}

__global__ __launch_bounds__(64) void k_scan2(const int* __restrict__ bsum,
                                              int* __restrict__ bpre)
{
  const int t = threadIdx.x;
  const int nb = (NN + 1023) / 1024;
  int v = (t < nb) ? bsum[t] : 0;
  int orig = v;
  #pragma unroll
  for (int off = 1; off < 64; off <<= 1){
    int u = __shfl_up(v, off);
    if (t >= off) v += u;
  }
  if (t < nb) bpre[t] = v - orig;
}

__global__ __launch_bounds__(1024) void k_scan3(int* __restrict__ cur,
                                                const int* __restrict__ bpre)
{
  const int idx = blockIdx.x * 1024 + threadIdx.x;
  if (idx < NN) cur[idx] += bpre[blockIdx.x];
}

__global__ __launch_bounds__(256) void k_scatter(const int* __restrict__ eidx,
                                                 int* __restrict__ cur,
                                                 int* __restrict__ perm)
{
  int e = blockIdx.x * 256 + threadIdx.x;
  if (e < NE){
    int d = eidx[NE + e];
    int p = atomicAdd(&cur[d], 1);
    perm[p] = e;
  }
}

// =============== one-time: materialize sorted edge streams ===============
__global__ __launch_bounds__(256) void k_permute(const int* __restrict__ perm,
                                                 const int* __restrict__ eidx,
                                                 const float* __restrict__ eattr,
                                                 int* __restrict__ src_s,
                                                 int* __restrict__ dst_s,
                                                 unsigned* __restrict__ eattr_bf)
{
  int i = blockIdx.x * 256 + threadIdx.x;
  if (i >= NE) return;
  int e = perm[i];
  src_s[i] = eidx[e];
  dst_s[i] = eidx[NE + e];
  const float* ea = eattr + (size_t)e * 16;
  float4 v0 = *(const float4*)(ea);
  float4 v1 = *(const float4*)(ea + 4);
  float4 v2 = *(const float4*)(ea + 8);
  float4 v3 = *(const float4*)(ea + 12);
  uint4 o0, o1;
  o0.x = packbf2(v0.x, v0.y); o0.y = packbf2(v0.z, v0.w);
  o0.z = packbf2(v1.x, v1.y); o0.w = packbf2(v1.z, v1.w);
  o1.x = packbf2(v2.x, v2.y); o1.y = packbf2(v2.z, v2.w);
  o1.z = packbf2(v3.x, v3.y); o1.w = packbf2(v3.z, v3.w);
  *(uint4*)(eattr_bf + (size_t)i * 8)     = o0;
  *(uint4*)(eattr_bf + (size_t)i * 8 + 4) = o1;
}

// =============== embed: h + h_bf ===============
__global__ __launch_bounds__(256) void k_embed(const float* __restrict__ x,
                                               const float* __restrict__ We,
                                               const float* __restrict__ be,
                                               float* __restrict__ h,
                                               unsigned* __restrict__ h_bf)
{
  const int t = threadIdx.x;
  const int j = t & 63, nd = t >> 6;
  const int node = blockIdx.x * 4 + nd;
  const float* xr = x + (size_t)node * AD;
  float acc = be[j];
  #pragma unroll 8
  for (int k = 0; k < AD; ++k)
    acc += xr[k] * We[k * HD + j];
  h[(size_t)node * HD + j] = acc;
  float p = __shfl_down(acc, 1);
  if (!(j & 1)) h_bf[(size_t)node * 32 + (j >> 1)] = packbf2(acc, p);
}

// =============== edge MLP (MFMA) — per-wave 16-edge tiles, persistent, XCD-chunked ===============
__global__ __launch_bounds__(256, 4) void k_edge(const unsigned* __restrict__ h_bf,
                                                 const int* __restrict__ src_s,
                                                 const int* __restrict__ dst_s,
                                                 const unsigned* __restrict__ eattr_bf,
                                                 const unsigned short* __restrict__ W1Tp,
                                                 const float* __restrict__ b1,
                                                 const unsigned* __restrict__ W2Tp32,
                                                 const float* __restrict__ b2,
                                                 float* __restrict__ agg)
{
  __shared__ __align__(16) unsigned short sW1T[64 * 168];
  __shared__ __align__(16) unsigned short sHid[4][16 * 72];   // per-wave hidden

  const int t = threadIdx.x;
  {
    const uint4* srcp = (const uint4*)W1Tp;
    uint4* dstp = (uint4*)sW1T;
    for (int i = t; i < 64 * 168 * 2 / 16; i += 256) dstp[i] = srcp[i];
  }
  __syncthreads();

  const int lane = t & 63, wv = t >> 6;
  const int m = lane & 15, q = lane >> 4;

  // W2 B-frags in VGPRs (n=lane&15, k=q*8+j)
  bf16x8 w2f[4][2];
  #pragma unroll
  for (int tl = 0; tl < 4; ++tl)
    #pragma unroll
    for (int ks = 0; ks < 2; ++ks)
      w2f[tl][ks] = ldfrag_g(W2Tp32 + (tl * 16 + m) * 36 + ks * 16 + q * 4);

  float b1v[4], b2v[4];
  #pragma unroll
  for (int tl = 0; tl < 4; ++tl){ b1v[tl] = b1[tl * 16 + m]; b2v[tl] = b2[tl * 16 + m]; }

  unsigned short* sHidW = sHid[wv];

  // XCD-contiguous chunking: block b -> xcd = b&7 handles tiles [xcd*TPX,(xcd+1)*TPX)
  const int xcd = blockIdx.x & 7, bi = blockIdx.x >> 3;
  for (int wt = xcd * TPX + bi * 4 + wv; wt < (xcd + 1) * TPX; wt += (EGRID / 8) * 4){
    const int base = wt * 16;
    const int src  = src_s[base + m];
    const int dstv = dst_s[base + m];

    // ---- A-frags ----
    bf16x8 af[5];
    const unsigned* hs = h_bf + (size_t)src  * 32;
    const unsigned* hd = h_bf + (size_t)dstv * 32;
    af[0] = ldfrag_g(hs + q * 4);
    af[1] = ldfrag_g(hs + 16 + q * 4);
    af[2] = ldfrag_g(hd + q * 4);
    af[3] = ldfrag_g(hd + 16 + q * 4);
    if (q < 2){
      af[4] = ldfrag_g(eattr_bf + (size_t)(base + m) * 8 + q * 4);
    } else {
      U4B x; x.u = make_uint4(0, 0, 0, 0); af[4] = x.v;
    }

    // ---- GEMM1: hidden = relu(in @ W1 + b1) ----
    f32x4 a0 = {0.f,0.f,0.f,0.f}, a1 = a0, a2 = a0, a3 = a0;
    #pragma unroll
    for (int ks = 0; ks < 5; ++ks){
      bf16x8 bb0 = *(const bf16x8*)&sW1T[( 0 + m) * 168 + ks * 32 + q * 8];
      bf16x8 bb1 = *(const bf16x8*)&sW1T[(16 + m) * 168 + ks * 32 + q * 8];
      bf16x8 bb2 = *(const bf16x8*)&sW1T[(32 + m) * 168 + ks * 32 + q * 8];
      bf16x8 bb3 = *(const bf16x8*)&sW1T[(48 + m) * 168 + ks * 32 + q * 8];
      a0 = __builtin_amdgcn_mfma_f32_16x16x32_bf16(af[ks], bb0, a0, 0, 0, 0);
      a1 = __builtin_amdgcn_mfma_f32_16x16x32_bf16(af[ks], bb1, a1, 0, 0, 0);
      a2 = __builtin_amdgcn_mfma_f32_16x16x32_bf16(af[ks], bb2, a2, 0, 0, 0);
      a3 = __builtin_amdgcn_mfma_f32_16x16x32_bf16(af[ks], bb3, a3, 0, 0, 0);
    }
    {
      f32x4 accs[4] = {a0, a1, a2, a3};
      #pragma unroll
      for (int tl = 0; tl < 4; ++tl)
        #pragma unroll
        for (int r = 0; r < 4; ++r)
          sHidW[(q * 4 + r) * 72 + tl * 16 + m] = f2bf(fmaxf(accs[tl][r] + b1v[tl], 0.f));
    }

    // ---- GEMM2: out = hidden @ W2 (B from VGPRs) ----
    f32x4 o0 = {0.f,0.f,0.f,0.f}, o1 = o0, o2 = o0, o3 = o0;
    #pragma unroll
    for (int ks = 0; ks < 2; ++ks){
      bf16x8 av = *(const bf16x8*)&sHidW[m * 72 + ks * 32 + q * 8];
      o0 = __builtin_amdgcn_mfma_f32_16x16x32_bf16(av, w2f[0][ks], o0, 0, 0, 0);
      o1 = __builtin_amdgcn_mfma_f32_16x16x32_bf16(av, w2f[1][ks], o1, 0, 0, 0);
      o2 = __builtin_amdgcn_mfma_f32_16x16x32_bf16(av, w2f[2][ks], o2, 0, 0, 0);
      o3 = __builtin_amdgcn_mfma_f32_16x16x32_bf16(av, w2f[3][ks], o3, 0, 0, 0);
    }

    // ---- segment reduce straight from C-frags (row=edge q*4+r, col=tl*16+m) ----
    int prev = __shfl_up(dstv, 1);
    bool isStart = (m == 0) || (dstv != prev);
    unsigned long long bal = __ballot(isStart);
    unsigned bs = (unsigned)bal & 0xFFFFu;
    int nr = __popc(bs);
    unsigned rem = bs & (bs - 1);
    int lo = 0;
    for (int r = 0; r < nr; ++r){
      int hi = rem ? (__ffs(rem) - 1) : 16;
      rem &= rem - 1;
      float s0 = 0.f, s1 = 0.f, s2 = 0.f, s3 = 0.f;
      #pragma unroll
      for (int rr = 0; rr < 4; ++rr){
        int row = q * 4 + rr;
        bool in = (row >= lo) && (row < hi);
        s0 += in ? o0[rr] : 0.f;
        s1 += in ? o1[rr] : 0.f;
        s2 += in ? o2[rr] : 0.f;
        s3 += in ? o3[rr] : 0.f;
      }
      s0 += __shfl_xor(s0, 16); s0 += __shfl_xor(s0, 32);
      s1 += __shfl_xor(s1, 16); s1 += __shfl_xor(s1, 32);
      s2 += __shfl_xor(s2, 16); s2 += __shfl_xor(s2, 32);
      s3 += __shfl_xor(s3, 16); s3 += __shfl_xor(s3, 32);
      int d = __shfl(dstv, lo);
      float cntf = (float)(hi - lo);
      if (q == 0){
        float v0 = s0 + cntf * b2v[0];
        float v1 = s1 + cntf * b2v[1];
        float v2 = s2 + cntf * b2v[2];
        float v3 = s3 + cntf * b2v[3];
        float* dp = &agg[(size_t)d * HD + m];
        if (r == 0 || r == nr - 1){
          atomicAdd(dp +  0, v0); atomicAdd(dp + 16, v1);
          atomicAdd(dp + 32, v2); atomicAdd(dp + 48, v3);
        } else {
          dp[ 0] = v0; dp[16] = v1; dp[32] = v2; dp[48] = v3;
        }
      }
      lo = hi;
    }
  }
}

// =============== GRU: persistent, weights staged once, kk-outer loop ===============
__global__ __launch_bounds__(256) void k_gru(const float* __restrict__ agg,
                                             float* __restrict__ h,
                                             unsigned* __restrict__ h_bf,
                                             const unsigned* __restrict__ Wihp,
                                             const float* __restrict__ bih,
                                             const unsigned* __restrict__ Whhp,
                                             const float* __restrict__ bhh)
{
  __shared__ unsigned sWi[192 * 33];
  __shared__ unsigned sWh[192 * 33];
  __shared__ float sA[16 * 64], sH[16 * 64];
  const int t = threadIdx.x;
  for (int i = t; i < 192 * 32; i += 256){
    int r = i >> 5, c = i & 31;
    sWi[r * 33 + c] = Wihp[i];
    sWh[r * 33 + c] = Whhp[i];
  }
  const int j = t & 63, wv = t >> 6;
  const float bir = bih[j], biz = bih[64 + j], bin_ = bih[128 + j];
  const float bhr = bhh[j], bhz = bhh[64 + j], bhn  = bhh[128 + j];

  for (int grp = blockIdx.x; grp < NN / 16; grp += GGRID){
    const int nb = grp * 16;
    __syncthreads();   // weights staged (first iter) / prior group reads done
    for (int i = t; i < 16 * 64; i += 256){
      int ln = i >> 6, c = i & 63;
      sA[i] = agg[(size_t)(nb + ln) * HD + c];
      sH[i] = h[(size_t)(nb + ln) * HD + c];
    }
    __syncthreads();

    float gr[4], gz[4], gn[4], hr_[4], hz_[4], hn_[4];
    #pragma unroll
    for (int i = 0; i < 4; ++i){
      gr[i] = bir; gz[i] = biz; gn[i] = bin_;
      hr_[i] = bhr; hz_[i] = bhz; hn_[i] = bhn;
    }
    for (int kk = 0; kk < 32; ++kk){
      unsigned wir = sWi[j * 33 + kk], wiz = sWi[(64 + j) * 33 + kk], win = sWi[(128 + j) * 33 + kk];
      unsigned whr = sWh[j * 33 + kk], whz = sWh[(64 + j) * 33 + kk], whn = sWh[(128 + j) * 33 + kk];
      float wirl = blo(wir), wirh = bhi(wir), wizl = blo(wiz), wizh = bhi(wiz);
      float winl = blo(win), winh = bhi(win), whrl = blo(whr), whrh = bhi(whr);
      float whzl = blo(whz), whzh = bhi(whz), whnl = blo(whn), whnh = bhi(whn);
      #pragma unroll
      for (int i = 0; i < 4; ++i){
        float2 av = *(const float2*)&sA[(wv + i * 4) * 64 + 2 * kk];
        float2 hv = *(const float2*)&sH[(wv + i * 4) * 64 + 2 * kk];
        gr[i]  += wirl * av.x + wirh * av.y;
        gz[i]  += wizl * av.x + wizh * av.y;
        gn[i]  += winl * av.x + winh * av.y;
        hr_[i] += whrl * hv.x + whrh * hv.y;
        hz_[i] += whzl * hv.x + whzh * hv.y;
        hn_[i] += whnl * hv.x + whnh * hv.y;
      }
    }
    #pragma unroll
    for (int i = 0; i < 4; ++i){
      int node = nb + wv + i * 4;
      float r = 1.f / (1.f + __expf(-(gr[i] + hr_[i])));
      float z = 1.f / (1.f + __expf(-(gz[i] + hz_[i])));
      float n = tanhf(gn[i] + r * hn_[i]);
      float hold = sH[(wv + i * 4) * 64 + j];
      float hnew = (1.f - z) * n + z * hold;
      h[(size_t)node * HD + j] = hnew;
      float p = __shfl_down(hnew, 1);
      if (!(j & 1)) h_bf[(size_t)node * 32 + (j >> 1)] = packbf2(hnew, p);
    }
  }
}

// =============== pool ===============
__global__ __launch_bounds__(256) void k_pool(const float* __restrict__ h,
                                              const int* __restrict__ batch,
                                              float* __restrict__ gsum,
                                              float* __restrict__ cnt)
{
  const int t = threadIdx.x;
  const int j = t & 63, r = t >> 6;
  const int n0 = blockIdx.x * 64 + r * 16;
  float acc = 0.f, c = 0.f;
  int cur = -1;
  for (int i = 0; i < 16; ++i){
    int n = n0 + i;
    if (n >= NN) break;
    int g = batch[n];
    if (g != cur){
      if (cur >= 0){
        atomicAdd(&gsum[cur * HD + j], acc);
        if (j == 0) atomicAdd(&cnt[cur], c);
      }
      cur = g; acc = 0.f; c = 0.f;
    }
    acc += h[(size_t)n * HD + j];
    c += 1.f;
  }
  if (cur >= 0){
    atomicAdd(&gsum[cur * HD + j], acc);
    if (j == 0) atomicAdd(&cnt[cur], c);
  }
}

// =============== head ===============
__global__ __launch_bounds__(64) void k_head(const float* __restrict__ gsum,
                                             const float* __restrict__ cnt,
                                             const float* __restrict__ W1,
                                             const float* __restrict__ b1,
                                             const float* __restrict__ W2,
                                             const float* __restrict__ b2,
                                             float* __restrict__ out)
{
  __shared__ float gv[128];
  const int g = blockIdx.x, j = threadIdx.x;
  float s = gsum[g * HD + j];
  float c = cnt[g];
  gv[j] = s;
  gv[64 + j] = s / fmaxf(c, 1.f);
  __syncthreads();
  float acc = b1[j];
  #pragma unroll 8
  for (int k = 0; k < 128; ++k)
    acc += gv[k] * W1[k * HD + j];
  acc = fmaxf(acc, 0.f);
  float v = acc * W2[j];
  #pragma unroll
  for (int off = 32; off; off >>= 1) v += __shfl_down(v, off, 64);
  if (j == 0) out[g] = v + b2[0];
}

extern "C" void kernel_launch(void* const* d_in, const int* in_sizes, int n_in,
                              void* d_out, int out_size, void* d_ws, size_t ws_size,
                              hipStream_t stream)
{
  (void)in_sizes; (void)n_in; (void)out_size; (void)ws_size;
  const float* x     = (const float*)d_in[0];
  const int*   eidx  = (const int*)d_in[1];
  const float* eattr = (const float*)d_in[2];
  const int*   batch = (const int*)d_in[3];
  const float* We    = (const float*)d_in[4];
  const float* be    = (const float*)d_in[5];
  const float* Wm1   = (const float*)d_in[6];
  const float* bm1   = (const float*)d_in[7];
  const float* Wm2   = (const float*)d_in[8];
  const float* bm2   = (const float*)d_in[9];
  const float* Wih   = (const float*)d_in[10];
  const float* bih   = (const float*)d_in[11];
  const float* Whh   = (const float*)d_in[12];
  const float* bhh   = (const float*)d_in[13];
  const float* Wh1   = (const float*)d_in[14];
  const float* bh1   = (const float*)d_in[15];
  const float* Wh2   = (const float*)d_in[16];
  const float* bh2   = (const float*)d_in[17];

  char* w = (char*)d_ws;
  float* h     = (float*)w;                      w += (size_t)NN * HD * 4;
  unsigned* h_bf = (unsigned*)w;                 w += (size_t)NN * 32 * 4;
  float* agg   = (float*)w;                      w += (size_t)NN * HD * 4;
  int*   deg   = (int*)w;                        w += (size_t)NN * 4;
  int*   cur   = (int*)w;                        w += (size_t)NN * 4;
  int*   perm  = (int*)w;                        w += (size_t)NE * 4;
  int*   src_s = (int*)w;                        w += (size_t)NE * 4;
  int*   dst_s = (int*)w;                        w += (size_t)NE * 4;
  unsigned* eattr_bf = (unsigned*)w;             w += (size_t)NE * 8 * 4;
  int*   bsum  = (int*)w;                        w += 64 * 4;
  int*   bpre  = (int*)w;                        w += 64 * 4;
  unsigned short* W1Tp = (unsigned short*)w;     w += 64 * 168 * 2;
  unsigned short* W2Tp = (unsigned short*)w;     w += 64 * 72 * 2;
  unsigned* Wihp = (unsigned*)w;                 w += 192 * 32 * 4;
  unsigned* Whhp = (unsigned*)w;                 w += 192 * 32 * 4;
  float* gsum  = (float*)w;                      w += (size_t)NG * HD * 4;
  float* cnt   = (float*)w;                      w += (size_t)NG * 4;

  const int nscanb = (NN + 1023) / 1024;

  k_prep<<<108, 256, 0, stream>>>(Wm1, Wm2, Wih, Whh, W1Tp, W2Tp, Wihp, Whhp);
  hipMemsetAsync(deg, 0, (size_t)NN * 4, stream);
  k_hist<<<(NE + 255) / 256, 256, 0, stream>>>(eidx, deg);
  k_scan1<<<nscanb, 1024, 0, stream>>>(deg, cur, bsum);
  k_scan2<<<1, 64, 0, stream>>>(bsum, bpre);
  k_scan3<<<nscanb, 1024, 0, stream>>>(cur, bpre);
  k_scatter<<<(NE + 255) / 256, 256, 0, stream>>>(eidx, cur, perm);
  k_permute<<<(NE + 255) / 256, 256, 0, stream>>>(perm, eidx, eattr, src_s, dst_s, eattr_bf);

  k_embed<<<NN / 4, 256, 0, stream>>>(x, We, be, h, h_bf);
  for (int s = 0; s < 3; ++s){
    hipMemsetAsync(agg, 0, (size_t)NN * HD * 4, stream);
    k_edge<<<EGRID, 256, 0, stream>>>(h_bf, src_s, dst_s, eattr_bf, W1Tp, bm1,
                                      (const unsigned*)W2Tp, bm2, agg);
    k_gru<<<GGRID, 256, 0, stream>>>(agg, h, h_bf, Wihp, bih, Whhp, bhh);
  }
  hipMemsetAsync(gsum, 0, (size_t)(NG * HD + NG) * 4, stream);
  k_pool<<<(NN + 63) / 64, 256, 0, stream>>>(h, batch, gsum, cnt);
  k_head<<<NG, 64, 0, stream>>>(gsum, cnt, Wh1, bh1, Wh2, bh2, (float*)d_out);
}

// Round 6
// 709.969 us; speedup vs baseline: 4.5101x; 1.4183x over previous
//
#include <hip/hip_runtime.h>
#include <math.h>

#define NN 50000
#define NE 800000
#define AD 32
#define ED 16
#define HD 64
#define NG 256
#define NTILES (NE / 16)     // 50000 wave-tiles of 16 edges
#define EGRID 1024           // persistent blocks for k_edge (128 per XCD)
#define TPX (NTILES / 8)     // tiles per XCD chunk
#define GGRID 512            // persistent blocks for k_gru
#define GTILES (NN / 16)     // 3125 gru node-tiles

typedef short bf16x8 __attribute__((ext_vector_type(8)));
typedef float f32x4  __attribute__((ext_vector_type(4)));
union U4B { uint4 u; bf16x8 v; };

__device__ __forceinline__ float b2f(unsigned short s){ return __uint_as_float(((unsigned)s) << 16); }
__device__ __forceinline__ unsigned short f2bf(float f){
  unsigned u = __float_as_uint(f);
  u += 0x7fffu + ((u >> 16) & 1u);          // RNE
  return (unsigned short)(u >> 16);
}
__device__ __forceinline__ unsigned packbf2(float a, float b){
  return (unsigned)f2bf(a) | ((unsigned)f2bf(b) << 16);
}
__device__ __forceinline__ bf16x8 ldfrag_g(const unsigned* p){
  U4B x; x.u = *(const uint4*)p; return x.v;
}

// =============== one-time prep: weights -> bf16 ===============
// W1Tp[n][k] 64x168 ; W2Tp[n][k] 64x72 ;
// Wgru frag-major: short[((ks*4+q)*384 + g)*8 + j], k=ks*32+q*8+j, g<192: Wih, else Whh
__global__ __launch_bounds__(256) void k_prep(const float* __restrict__ W1,
                                              const float* __restrict__ W2,
                                              const float* __restrict__ Wih,
                                              const float* __restrict__ Whh,
                                              unsigned short* __restrict__ W1Tp,
                                              unsigned short* __restrict__ W2Tp,
                                              unsigned short* __restrict__ Wgru)
{
  int idx = blockIdx.x * 256 + threadIdx.x;
  if (idx < 64 * 168){
    int n = idx / 168, k = idx % 168;
    W1Tp[idx] = (k < 144) ? f2bf(W1[k * 64 + n]) : (unsigned short)0;
    return;
  }
  idx -= 64 * 168;
  if (idx < 64 * 72){
    int n = idx / 72, k = idx % 72;
    W2Tp[idx] = (k < 64) ? f2bf(W2[k * 64 + n]) : (unsigned short)0;
    return;
  }
  idx -= 64 * 72;
  if (idx < 384 * 64){
    int j = idx & 7;
    int g = (idx >> 3) % 384;
    int blk = idx >> 3; blk /= 384;         // 0..7
    int q = blk & 3, ks = blk >> 2;
    int k = ks * 32 + q * 8 + j;
    float v = (g < 192) ? Wih[g * 64 + k] : Whh[(g - 192) * 64 + k];
    Wgru[idx] = f2bf(v);
  }
}

// =============== CSR build ===============
__global__ __launch_bounds__(256) void k_hist(const int* __restrict__ eidx, int* __restrict__ deg)
{
  int e = blockIdx.x * 256 + threadIdx.x;
  if (e < NE) atomicAdd(&deg[eidx[NE + e]], 1);
}

__global__ __launch_bounds__(1024) void k_scan1(const int* __restrict__ deg,
                                                int* __restrict__ cur,
                                                int* __restrict__ bsum)
{
  __shared__ int s[1024];
  const int t = threadIdx.x;
  const int idx = blockIdx.x * 1024 + t;
  int v = (idx < NN) ? deg[idx] : 0;
  s[t] = v;
  __syncthreads();
  for (int d = 1; d < 1024; d <<= 1){
    int y = (t >= d) ? s[t - d] : 0;
    __syncthreads();
    s[t] += y;
    __syncthreads();
  }
  if (idx < NN) cur[idx] = s[t] - v;
  if (t == 1023) bsum[blockIdx.x] = s[1023];
}

__global__ __launch_bounds__(64) void k_scan2(const int* __restrict__ bsum,
                                              int* __restrict__ bpre)
{
  const int t = threadIdx.x;
  const int nb = (NN + 1023) / 1024;
  int v = (t < nb) ? bsum[t] : 0;
  int orig = v;
  #pragma unroll
  for (int off = 1; off < 64; off <<= 1){
    int u = __shfl_up(v, off);
    if (t >= off) v += u;
  }
  if (t < nb) bpre[t] = v - orig;
}

__global__ __launch_bounds__(1024) void k_scan3(int* __restrict__ cur,
                                                const int* __restrict__ bpre)
{
  const int idx = blockIdx.x * 1024 + threadIdx.x;
  if (idx < NN) cur[idx] += bpre[blockIdx.x];
}

// fused scatter: directly emit sorted streams (no perm / second pass)
__global__ __launch_bounds__(256) void k_scatter(const int* __restrict__ eidx,
                                                 const float* __restrict__ eattr,
                                                 int* __restrict__ cur,
                                                 int* __restrict__ src_s,
                                                 int* __restrict__ dst_s,
                                                 unsigned* __restrict__ eattr_bf)
{
  int e = blockIdx.x * 256 + threadIdx.x;
  if (e >= NE) return;
  int d = eidx[NE + e];
  int p = atomicAdd(&cur[d], 1);
  src_s[p] = eidx[e];
  dst_s[p] = d;
  const float* ea = eattr + (size_t)e * 16;
  float4 v0 = *(const float4*)(ea);
  float4 v1 = *(const float4*)(ea + 4);
  float4 v2 = *(const float4*)(ea + 8);
  float4 v3 = *(const float4*)(ea + 12);
  uint4 o0, o1;
  o0.x = packbf2(v0.x, v0.y); o0.y = packbf2(v0.z, v0.w);
  o0.z = packbf2(v1.x, v1.y); o0.w = packbf2(v1.z, v1.w);
  o1.x = packbf2(v2.x, v2.y); o1.y = packbf2(v2.z, v2.w);
  o1.z = packbf2(v3.x, v3.y); o1.w = packbf2(v3.z, v3.w);
  *(uint4*)(eattr_bf + (size_t)p * 8)     = o0;
  *(uint4*)(eattr_bf + (size_t)p * 8 + 4) = o1;
}

// =============== embed: h + h_bf ===============
__global__ __launch_bounds__(256) void k_embed(const float* __restrict__ x,
                                               const float* __restrict__ We,
                                               const float* __restrict__ be,
                                               float* __restrict__ h,
                                               unsigned* __restrict__ h_bf)
{
  const int t = threadIdx.x;
  const int j = t & 63, nd = t >> 6;
  const int node = blockIdx.x * 4 + nd;
  const float* xr = x + (size_t)node * AD;
  float acc = be[j];
  #pragma unroll 8
  for (int k = 0; k < AD; ++k)
    acc += xr[k] * We[k * HD + j];
  h[(size_t)node * HD + j] = acc;
  float p = __shfl_down(acc, 1);
  if (!(j & 1)) h_bf[(size_t)node * 32 + (j >> 1)] = packbf2(acc, p);
}

// =============== edge MLP (MFMA) — prefetch-pipelined per-wave tiles ===============
__global__ __launch_bounds__(256, 3) void k_edge(const unsigned* __restrict__ h_bf,
                                                 const int* __restrict__ src_s,
                                                 const int* __restrict__ dst_s,
                                                 const unsigned* __restrict__ eattr_bf,
                                                 const unsigned short* __restrict__ W1Tp,
                                                 const float* __restrict__ b1,
                                                 const unsigned* __restrict__ W2Tp32,
                                                 const float* __restrict__ b2,
                                                 float* __restrict__ agg)
{
  __shared__ __align__(16) unsigned short sW1T[64 * 168];
  __shared__ __align__(16) unsigned short sHid[4][16 * 72];

  const int t = threadIdx.x;
  {
    const uint4* srcp = (const uint4*)W1Tp;
    uint4* dstp = (uint4*)sW1T;
    for (int i = t; i < 64 * 168 * 2 / 16; i += 256) dstp[i] = srcp[i];
  }
  __syncthreads();

  const int lane = t & 63, wv = t >> 6;
  const int m = lane & 15, q = lane >> 4;

  bf16x8 w2f[4][2];
  #pragma unroll
  for (int tl = 0; tl < 4; ++tl)
    #pragma unroll
    for (int ks = 0; ks < 2; ++ks)
      w2f[tl][ks] = ldfrag_g(W2Tp32 + (tl * 16 + m) * 36 + ks * 16 + q * 4);

  float b1v[4], b2v[4];
  #pragma unroll
  for (int tl = 0; tl < 4; ++tl){ b1v[tl] = b1[tl * 16 + m]; b2v[tl] = b2[tl * 16 + m]; }

  unsigned short* sHidW = sHid[wv];

  const int xcd = blockIdx.x & 7, bi = blockIdx.x >> 3;
  const int wend = (xcd + 1) * TPX;
  const int wstep = (EGRID / 8) * 4;
  int wt = xcd * TPX + bi * 4 + wv;

  // preload tile 0
  int scur = src_s[wt * 16 + m];
  int dcur = dst_s[wt * 16 + m];
  bf16x8 afc[5];
  {
    const unsigned* hs = h_bf + (size_t)scur * 32;
    const unsigned* hd = h_bf + (size_t)dcur * 32;
    afc[0] = ldfrag_g(hs + q * 4);
    afc[1] = ldfrag_g(hs + 16 + q * 4);
    afc[2] = ldfrag_g(hd + q * 4);
    afc[3] = ldfrag_g(hd + 16 + q * 4);
    if (q < 2) afc[4] = ldfrag_g(eattr_bf + (size_t)(wt * 16 + m) * 8 + q * 4);
    else { U4B x; x.u = make_uint4(0,0,0,0); afc[4] = x.v; }
  }

  while (wt < wend){
    const int wn = wt + wstep;
    const bool hasn = (wn < wend);
    int sn = 0, dn = 0;
    if (hasn){ sn = src_s[wn * 16 + m]; dn = dst_s[wn * 16 + m]; }

    // ---- GEMM1 ----
    f32x4 a0 = {0.f,0.f,0.f,0.f}, a1 = a0, a2 = a0, a3 = a0;
    #pragma unroll
    for (int ks = 0; ks < 5; ++ks){
      bf16x8 bb0 = *(const bf16x8*)&sW1T[( 0 + m) * 168 + ks * 32 + q * 8];
      bf16x8 bb1 = *(const bf16x8*)&sW1T[(16 + m) * 168 + ks * 32 + q * 8];
      bf16x8 bb2 = *(const bf16x8*)&sW1T[(32 + m) * 168 + ks * 32 + q * 8];
      bf16x8 bb3 = *(const bf16x8*)&sW1T[(48 + m) * 168 + ks * 32 + q * 8];
      a0 = __builtin_amdgcn_mfma_f32_16x16x32_bf16(afc[ks], bb0, a0, 0, 0, 0);
      a1 = __builtin_amdgcn_mfma_f32_16x16x32_bf16(afc[ks], bb1, a1, 0, 0, 0);
      a2 = __builtin_amdgcn_mfma_f32_16x16x32_bf16(afc[ks], bb2, a2, 0, 0, 0);
      a3 = __builtin_amdgcn_mfma_f32_16x16x32_bf16(afc[ks], bb3, a3, 0, 0, 0);
    }
    {
      f32x4 accs[4] = {a0, a1, a2, a3};
      #pragma unroll
      for (int tl = 0; tl < 4; ++tl)
        #pragma unroll
        for (int r = 0; r < 4; ++r)
          sHidW[(q * 4 + r) * 72 + tl * 16 + m] = f2bf(fmaxf(accs[tl][r] + b1v[tl], 0.f));
    }

    // ---- prefetch next tile's A-frags (indices have landed during GEMM1) ----
    bf16x8 afn[5];
    if (hasn){
      const unsigned* hs = h_bf + (size_t)sn * 32;
      const unsigned* hd = h_bf + (size_t)dn * 32;
      afn[0] = ldfrag_g(hs + q * 4);
      afn[1] = ldfrag_g(hs + 16 + q * 4);
      afn[2] = ldfrag_g(hd + q * 4);
      afn[3] = ldfrag_g(hd + 16 + q * 4);
      if (q < 2) afn[4] = ldfrag_g(eattr_bf + (size_t)(wn * 16 + m) * 8 + q * 4);
      else { U4B x; x.u = make_uint4(0,0,0,0); afn[4] = x.v; }
    }

    // ---- GEMM2 ----
    f32x4 o0 = {0.f,0.f,0.f,0.f}, o1 = o0, o2 = o0, o3 = o0;
    #pragma unroll
    for (int ks = 0; ks < 2; ++ks){
      bf16x8 av = *(const bf16x8*)&sHidW[m * 72 + ks * 32 + q * 8];
      o0 = __builtin_amdgcn_mfma_f32_16x16x32_bf16(av, w2f[0][ks], o0, 0, 0, 0);
      o1 = __builtin_amdgcn_mfma_f32_16x16x32_bf16(av, w2f[1][ks], o1, 0, 0, 0);
      o2 = __builtin_amdgcn_mfma_f32_16x16x32_bf16(av, w2f[2][ks], o2, 0, 0, 0);
      o3 = __builtin_amdgcn_mfma_f32_16x16x32_bf16(av, w2f[3][ks], o3, 0, 0, 0);
    }

    // ---- segment reduce from C-frags ----
    int prev = __shfl_up(dcur, 1);
    bool isStart = (m == 0) || (dcur != prev);
    unsigned long long bal = __ballot(isStart);
    unsigned bs = (unsigned)bal & 0xFFFFu;
    int nr = __popc(bs);
    unsigned rem = bs & (bs - 1);
    int lo = 0;
    for (int r = 0; r < nr; ++r){
      int hi = rem ? (__ffs(rem) - 1) : 16;
      rem &= rem - 1;
      float s0 = 0.f, s1 = 0.f, s2 = 0.f, s3 = 0.f;
      #pragma unroll
      for (int rr = 0; rr < 4; ++rr){
        int row = q * 4 + rr;
        bool in = (row >= lo) && (row < hi);
        s0 += in ? o0[rr] : 0.f;
        s1 += in ? o1[rr] : 0.f;
        s2 += in ? o2[rr] : 0.f;
        s3 += in ? o3[rr] : 0.f;
      }
      s0 += __shfl_xor(s0, 16); s0 += __shfl_xor(s0, 32);
      s1 += __shfl_xor(s1, 16); s1 += __shfl_xor(s1, 32);
      s2 += __shfl_xor(s2, 16); s2 += __shfl_xor(s2, 32);
      s3 += __shfl_xor(s3, 16); s3 += __shfl_xor(s3, 32);
      int d = __shfl(dcur, lo);
      float cntf = (float)(hi - lo);
      if (q == 0){
        float v0 = s0 + cntf * b2v[0];
        float v1 = s1 + cntf * b2v[1];
        float v2 = s2 + cntf * b2v[2];
        float v3 = s3 + cntf * b2v[3];
        float* dp = &agg[(size_t)d * HD + m];
        if (r == 0 || r == nr - 1){
          atomicAdd(dp +  0, v0); atomicAdd(dp + 16, v1);
          atomicAdd(dp + 32, v2); atomicAdd(dp + 48, v3);
        } else {
          dp[ 0] = v0; dp[16] = v1; dp[32] = v2; dp[48] = v3;
        }
      }
      lo = hi;
    }

    wt = wn; scur = sn; dcur = dn;
    #pragma unroll
    for (int i = 0; i < 5; ++i) afc[i] = afn[i];
  }
}

// =============== GRU via MFMA: per-wave 16-node tiles ===============
__global__ __launch_bounds__(256) void k_gru(const float* __restrict__ agg,
                                             float* __restrict__ h,
                                             unsigned* __restrict__ h_bf,
                                             const unsigned short* __restrict__ Wgru,
                                             const float* __restrict__ bih,
                                             const float* __restrict__ bhh)
{
  __shared__ __align__(16) unsigned short sWg[384 * 64];   // frag-major [(ks*4+q)][g][8]
  __shared__ __align__(16) unsigned sAg[4][16 * 32];       // per-wave agg bf16 [node][k/2]

  const int t = threadIdx.x;
  {
    const uint4* srcp = (const uint4*)Wgru;
    uint4* dstp = (uint4*)sWg;
    for (int i = t; i < 384 * 64 * 2 / 16; i += 256) dstp[i] = srcp[i];
  }
  __syncthreads();

  const int lane = t & 63, wv = t >> 6;
  const int m = lane & 15, q = lane >> 4;

  float bi_r[4], bi_z[4], bi_n[4], bh_r[4], bh_z[4], bh_n[4];
  #pragma unroll
  for (int tl = 0; tl < 4; ++tl){
    bi_r[tl] = bih[tl * 16 + m];  bi_z[tl] = bih[64 + tl * 16 + m];  bi_n[tl] = bih[128 + tl * 16 + m];
    bh_r[tl] = bhh[tl * 16 + m];  bh_z[tl] = bhh[64 + tl * 16 + m];  bh_n[tl] = bhh[128 + tl * 16 + m];
  }

  unsigned* aw = sAg[wv];

  for (int wt = blockIdx.x * 4 + wv; wt < GTILES; wt += GGRID * 4){
    const int n0 = wt * 16;

    // stage agg tile -> bf16 LDS (lane L: node L/4, k (L%4)*16..)
    {
      const float4* ap = (const float4*)(agg + (size_t)n0 * HD + lane * 16);
      float4 v0 = ap[0], v1 = ap[1], v2 = ap[2], v3 = ap[3];
      uint4 o0, o1;
      o0.x = packbf2(v0.x, v0.y); o0.y = packbf2(v0.z, v0.w);
      o0.z = packbf2(v1.x, v1.y); o0.w = packbf2(v1.z, v1.w);
      o1.x = packbf2(v2.x, v2.y); o1.y = packbf2(v2.z, v2.w);
      o1.z = packbf2(v3.x, v3.y); o1.w = packbf2(v3.z, v3.w);
      *(uint4*)(aw + lane * 8)     = o0;
      *(uint4*)(aw + lane * 8 + 4) = o1;
    }
    asm volatile("s_waitcnt lgkmcnt(0)" ::: "memory");

    // A-frags
    bf16x8 aA[2], aH[2];
    #pragma unroll
    for (int ks = 0; ks < 2; ++ks){
      aA[ks] = ldfrag_g(aw + m * 32 + ks * 16 + q * 4);   // LDS (cast ok: contiguous 16B)
      aH[ks] = ldfrag_g(h_bf + (size_t)(n0 + m) * 32 + ks * 16 + q * 4);
    }

    // GEMMs: ci = agg@Wih^T (N=192), ch = h@Whh^T
    f32x4 ci[12], ch[12];
    #pragma unroll
    for (int tl = 0; tl < 12; ++tl){ ci[tl] = f32x4{0.f,0.f,0.f,0.f}; ch[tl] = ci[tl]; }
    #pragma unroll
    for (int ks = 0; ks < 2; ++ks){
      #pragma unroll
      for (int tl = 0; tl < 12; ++tl){
        bf16x8 bi = *(const bf16x8*)&sWg[((ks * 4 + q) * 384 + tl * 16 + m) * 8];
        ci[tl] = __builtin_amdgcn_mfma_f32_16x16x32_bf16(aA[ks], bi, ci[tl], 0, 0, 0);
        bf16x8 bh = *(const bf16x8*)&sWg[((ks * 4 + q) * 384 + 192 + tl * 16 + m) * 8];
        ch[tl] = __builtin_amdgcn_mfma_f32_16x16x32_bf16(aH[ks], bh, ch[tl], 0, 0, 0);
      }
    }

    // epilogue: gates at C coords col=tl*16+m (gate), row=q*4+rr (node)
    #pragma unroll
    for (int tl = 0; tl < 4; ++tl){
      #pragma unroll
      for (int rr = 0; rr < 4; ++rr){
        const int node = n0 + q * 4 + rr;
        float ir = ci[tl][rr]     + bi_r[tl], hr = ch[tl][rr]     + bh_r[tl];
        float iz = ci[4 + tl][rr] + bi_z[tl], hz = ch[4 + tl][rr] + bh_z[tl];
        float in_ = ci[8 + tl][rr] + bi_n[tl], hn = ch[8 + tl][rr] + bh_n[tl];
        float rg = 1.f / (1.f + __expf(-(ir + hr)));
        float zg = 1.f / (1.f + __expf(-(iz + hz)));
        float ng = tanhf(in_ + rg * hn);
        float hold = h[(size_t)node * HD + tl * 16 + m];
        float hnew = (1.f - zg) * ng + zg * hold;
        h[(size_t)node * HD + tl * 16 + m] = hnew;
        float pp = __shfl_xor(hnew, 1);
        if (!(m & 1))
          h_bf[(size_t)node * 32 + tl * 8 + (m >> 1)] = packbf2(hnew, pp);
      }
    }
  }
}

// =============== pool ===============
__global__ __launch_bounds__(256) void k_pool(const float* __restrict__ h,
                                              const int* __restrict__ batch,
                                              float* __restrict__ gsum,
                                              float* __restrict__ cnt)
{
  const int t = threadIdx.x;
  const int j = t & 63, r = t >> 6;
  const int n0 = blockIdx.x * 64 + r * 16;
  float acc = 0.f, c = 0.f;
  int cur = -1;
  for (int i = 0; i < 16; ++i){
    int n = n0 + i;
    if (n >= NN) break;
    int g = batch[n];
    if (g != cur){
      if (cur >= 0){
        atomicAdd(&gsum[cur * HD + j], acc);
        if (j == 0) atomicAdd(&cnt[cur], c);
      }
      cur = g; acc = 0.f; c = 0.f;
    }
    acc += h[(size_t)n * HD + j];
    c += 1.f;
  }
  if (cur >= 0){
    atomicAdd(&gsum[cur * HD + j], acc);
    if (j == 0) atomicAdd(&cnt[cur], c);
  }
}

// =============== head ===============
__global__ __launch_bounds__(64) void k_head(const float* __restrict__ gsum,
                                             const float* __restrict__ cnt,
                                             const float* __restrict__ W1,
                                             const float* __restrict__ b1,
                                             const float* __restrict__ W2,
                                             const float* __restrict__ b2,
                                             float* __restrict__ out)
{
  __shared__ float gv[128];
  const int g = blockIdx.x, j = threadIdx.x;
  float s = gsum[g * HD + j];
  float c = cnt[g];
  gv[j] = s;
  gv[64 + j] = s / fmaxf(c, 1.f);
  __syncthreads();
  float acc = b1[j];
  #pragma unroll 8
  for (int k = 0; k < 128; ++k)
    acc += gv[k] * W1[k * HD + j];
  acc = fmaxf(acc, 0.f);
  float v = acc * W2[j];
  #pragma unroll
  for (int off = 32; off; off >>= 1) v += __shfl_down(v, off, 64);
  if (j == 0) out[g] = v + b2[0];
}

extern "C" void kernel_launch(void* const* d_in, const int* in_sizes, int n_in,
                              void* d_out, int out_size, void* d_ws, size_t ws_size,
                              hipStream_t stream)
{
  (void)in_sizes; (void)n_in; (void)out_size; (void)ws_size;
  const float* x     = (const float*)d_in[0];
  const int*   eidx  = (const int*)d_in[1];
  const float* eattr = (const float*)d_in[2];
  const int*   batch = (const int*)d_in[3];
  const float* We    = (const float*)d_in[4];
  const float* be    = (const float*)d_in[5];
  const float* Wm1   = (const float*)d_in[6];
  const float* bm1   = (const float*)d_in[7];
  const float* Wm2   = (const float*)d_in[8];
  const float* bm2   = (const float*)d_in[9];
  const float* Wih   = (const float*)d_in[10];
  const float* bih   = (const float*)d_in[11];
  const float* Whh   = (const float*)d_in[12];
  const float* bhh   = (const float*)d_in[13];
  const float* Wh1   = (const float*)d_in[14];
  const float* bh1   = (const float*)d_in[15];
  const float* Wh2   = (const float*)d_in[16];
  const float* bh2   = (const float*)d_in[17];

  char* w = (char*)d_ws;
  float* h     = (float*)w;                      w += (size_t)NN * HD * 4;
  unsigned* h_bf = (unsigned*)w;                 w += (size_t)NN * 32 * 4;
  float* agg   = (float*)w;                      w += (size_t)NN * HD * 4;
  int*   deg   = (int*)w;                        w += (size_t)NN * 4;
  int*   cur   = (int*)w;                        w += (size_t)NN * 4;
  int*   src_s = (int*)w;                        w += (size_t)NE * 4;
  int*   dst_s = (int*)w;                        w += (size_t)NE * 4;
  unsigned* eattr_bf = (unsigned*)w;             w += (size_t)NE * 8 * 4;
  int*   bsum  = (int*)w;                        w += 64 * 4;
  int*   bpre  = (int*)w;                        w += 64 * 4;
  unsigned short* W1Tp = (unsigned short*)w;     w += 64 * 168 * 2;
  unsigned short* W2Tp = (unsigned short*)w;     w += 64 * 72 * 2;
  unsigned short* Wgru = (unsigned short*)w;     w += 384 * 64 * 2;
  float* gsum  = (float*)w;                      w += (size_t)NG * HD * 4;
  float* cnt   = (float*)w;                      w += (size_t)NG * 4;

  const int nscanb = (NN + 1023) / 1024;

  k_prep<<<156, 256, 0, stream>>>(Wm1, Wm2, Wih, Whh, W1Tp, W2Tp, Wgru);
  hipMemsetAsync(deg, 0, (size_t)NN * 4, stream);
  k_hist<<<(NE + 255) / 256, 256, 0, stream>>>(eidx, deg);
  k_scan1<<<nscanb, 1024, 0, stream>>>(deg, cur, bsum);
  k_scan2<<<1, 64, 0, stream>>>(bsum, bpre);
  k_scan3<<<nscanb, 1024, 0, stream>>>(cur, bpre);
  k_scatter<<<(NE + 255) / 256, 256, 0, stream>>>(eidx, eattr, cur, src_s, dst_s, eattr_bf);

  k_embed<<<NN / 4, 256, 0, stream>>>(x, We, be, h, h_bf);
  for (int s = 0; s < 3; ++s){
    hipMemsetAsync(agg, 0, (size_t)NN * HD * 4, stream);
    k_edge<<<EGRID, 256, 0, stream>>>(h_bf, src_s, dst_s, eattr_bf, W1Tp, bm1,
                                      (const unsigned*)W2Tp, bm2, agg);
    k_gru<<<GGRID, 256, 0, stream>>>(agg, h, h_bf, Wgru, bih, bhh);
  }
  hipMemsetAsync(gsum, 0, (size_t)(NG * HD + NG) * 4, stream);
  k_pool<<<(NN + 63) / 64, 256, 0, stream>>>(h, batch, gsum, cnt);
  k_head<<<NG, 64, 0, stream>>>(gsum, cnt, Wh1, bh1, Wh2, bh2, (float*)d_out);
}

// Round 7
// 578.565 us; speedup vs baseline: 5.5344x; 1.2271x over previous
//
#include <hip/hip_runtime.h>
#include <math.h>

#define NN 50000
#define NE 800000
#define AD 32
#define ED 16
#define HD 64
#define NG 256
#define NTILES (NE / 16)     // 50000 wave-tiles of 16 edges
#define EGRID 1280           // persistent blocks for new k_edge
#define EGRID_FB 1024        // fallback k_edge grid
#define TPX (NTILES / 8)     // tiles per XCD chunk
#define GGRID 768            // persistent blocks for k_gru (3 per CU)
#define GTILES (NN / 16)     // 3125 gru node-tiles
#define PGRID 782            // k_pre blocks

typedef short bf16x8 __attribute__((ext_vector_type(8)));
typedef float f32x4  __attribute__((ext_vector_type(4)));
union U4B { uint4 u; bf16x8 v; };

__device__ __forceinline__ float blo(unsigned u){ return __uint_as_float(u << 16); }
__device__ __forceinline__ float bhi(unsigned u){ return __uint_as_float(u & 0xffff0000u); }
__device__ __forceinline__ unsigned short f2bf(float f){
  unsigned u = __float_as_uint(f);
  u += 0x7fffu + ((u >> 16) & 1u);          // RNE
  return (unsigned short)(u >> 16);
}
__device__ __forceinline__ unsigned packbf2(float a, float b){
  return (unsigned)f2bf(a) | ((unsigned)f2bf(b) << 16);
}
__device__ __forceinline__ bf16x8 ldfrag_g(const unsigned* p){
  U4B x; x.u = *(const uint4*)p; return x.v;
}
// relu(a+b+c) on packed bf16 pairs -> packed bf16
__device__ __forceinline__ unsigned srp1(unsigned a, unsigned b, unsigned c){
  float lo = fmaxf(blo(a) + blo(b) + blo(c), 0.f);
  float hi = fmaxf(bhi(a) + bhi(b) + bhi(c), 0.f);
  return packbf2(lo, hi);
}
__device__ __forceinline__ bf16x8 srp4(uint4 a, uint4 b, uint4 c){
  U4B r;
  r.u.x = srp1(a.x, b.x, c.x);
  r.u.y = srp1(a.y, b.y, c.y);
  r.u.z = srp1(a.z, b.z, c.z);
  r.u.w = srp1(a.w, b.w, c.w);
  return r.v;
}

// =============== one-time prep: weights -> bf16 ===============
// W1Tp[n][k] 64x168 ; W2Tp[n][k] 64x72 ; Wgru frag-major ; W1cTp[n][k] 64x32 (k<16: W1c, k==16: b1)
__global__ __launch_bounds__(256) void k_prep(const float* __restrict__ W1,
                                              const float* __restrict__ W2,
                                              const float* __restrict__ Wih,
                                              const float* __restrict__ Whh,
                                              const float* __restrict__ b1,
                                              unsigned short* __restrict__ W1Tp,
                                              unsigned short* __restrict__ W2Tp,
                                              unsigned short* __restrict__ Wgru,
                                              unsigned short* __restrict__ W1cTp)
{
  int idx = blockIdx.x * 256 + threadIdx.x;
  if (idx < 64 * 168){
    int n = idx / 168, k = idx % 168;
    W1Tp[idx] = (k < 144) ? f2bf(W1[k * 64 + n]) : (unsigned short)0;
    return;
  }
  idx -= 64 * 168;
  if (idx < 64 * 72){
    int n = idx / 72, k = idx % 72;
    W2Tp[idx] = (k < 64) ? f2bf(W2[k * 64 + n]) : (unsigned short)0;
    return;
  }
  idx -= 64 * 72;
  if (idx < 384 * 64){
    int j = idx & 7;
    int g = (idx >> 3) % 384;
    int blk = idx >> 3; blk /= 384;         // 0..7
    int q = blk & 3, ks = blk >> 2;
    int k = ks * 32 + q * 8 + j;
    float v = (g < 192) ? Wih[g * 64 + k] : Whh[(g - 192) * 64 + k];
    Wgru[idx] = f2bf(v);
    return;
  }
  idx -= 384 * 64;
  if (idx < 64 * 32){
    int n = idx / 32, k = idx % 32;
    float v = (k < 16) ? W1[(128 + k) * 64 + n] : (k == 16 ? b1[n] : 0.f);
    W1cTp[idx] = f2bf(v);
  }
}

// =============== CSR build ===============
__global__ __launch_bounds__(256) void k_hist(const int* __restrict__ eidx, int* __restrict__ deg)
{
  int e = blockIdx.x * 256 + threadIdx.x;
  if (e < NE) atomicAdd(&deg[eidx[NE + e]], 1);
}

__global__ __launch_bounds__(1024) void k_scan1(const int* __restrict__ deg,
                                                int* __restrict__ cur,
                                                int* __restrict__ bsum)
{
  __shared__ int s[1024];
  const int t = threadIdx.x;
  const int idx = blockIdx.x * 1024 + t;
  int v = (idx < NN) ? deg[idx] : 0;
  s[t] = v;
  __syncthreads();
  for (int d = 1; d < 1024; d <<= 1){
    int y = (t >= d) ? s[t - d] : 0;
    __syncthreads();
    s[t] += y;
    __syncthreads();
  }
  if (idx < NN) cur[idx] = s[t] - v;
  if (t == 1023) bsum[blockIdx.x] = s[1023];
}

__global__ __launch_bounds__(64) void k_scan2(const int* __restrict__ bsum,
                                              int* __restrict__ bpre)
{
  const int t = threadIdx.x;
  const int nb = (NN + 1023) / 1024;
  int v = (t < nb) ? bsum[t] : 0;
  int orig = v;
  #pragma unroll
  for (int off = 1; off < 64; off <<= 1){
    int u = __shfl_up(v, off);
    if (t >= off) v += u;
  }
  if (t < nb) bpre[t] = v - orig;
}

__global__ __launch_bounds__(1024) void k_scan3(int* __restrict__ cur,
                                                const int* __restrict__ bpre)
{
  const int idx = blockIdx.x * 1024 + threadIdx.x;
  if (idx < NN) cur[idx] += bpre[blockIdx.x];
}

// fused scatter: directly emit sorted streams
__global__ __launch_bounds__(256) void k_scatter(const int* __restrict__ eidx,
                                                 const float* __restrict__ eattr,
                                                 int* __restrict__ cur,
                                                 int* __restrict__ src_s,
                                                 int* __restrict__ dst_s,
                                                 unsigned* __restrict__ eattr_bf)
{
  int e = blockIdx.x * 256 + threadIdx.x;
  if (e >= NE) return;
  int d = eidx[NE + e];
  int p = atomicAdd(&cur[d], 1);
  src_s[p] = eidx[e];
  dst_s[p] = d;
  const float* ea = eattr + (size_t)e * 16;
  float4 v0 = *(const float4*)(ea);
  float4 v1 = *(const float4*)(ea + 4);
  float4 v2 = *(const float4*)(ea + 8);
  float4 v3 = *(const float4*)(ea + 12);
  uint4 o0, o1;
  o0.x = packbf2(v0.x, v0.y); o0.y = packbf2(v0.z, v0.w);
  o0.z = packbf2(v1.x, v1.y); o0.w = packbf2(v1.z, v1.w);
  o1.x = packbf2(v2.x, v2.y); o1.y = packbf2(v2.z, v2.w);
  o1.z = packbf2(v3.x, v3.y); o1.w = packbf2(v3.z, v3.w);
  *(uint4*)(eattr_bf + (size_t)p * 8)     = o0;
  *(uint4*)(eattr_bf + (size_t)p * 8 + 4) = o1;
}

// =============== once: E1[e] = eattr@W1c + b1 (sorted order, A-frag friendly) ===============
__global__ __launch_bounds__(256) void k_eprep(const unsigned* __restrict__ eattr_bf,
                                               const unsigned* __restrict__ W1cTp32,
                                               unsigned* __restrict__ E1)
{
  const int t = threadIdx.x, lane = t & 63, wv = t >> 6;
  const int m = lane & 15, q = lane >> 4;
  bf16x8 wf[4];
  #pragma unroll
  for (int tl = 0; tl < 4; ++tl)
    wf[tl] = ldfrag_g(W1cTp32 + (tl * 16 + m) * 16 + q * 4);

  for (int wt = blockIdx.x * 4 + wv; wt < NTILES; wt += 1024 * 4){
    const int base = wt * 16;
    U4B x;
    if (q < 2)      x.u = *(const uint4*)(eattr_bf + (size_t)(base + m) * 8 + q * 4);
    else if (q == 2) x.u = make_uint4(0x3F80u, 0, 0, 0);   // k=16 -> 1.0 (bias slot)
    else             x.u = make_uint4(0, 0, 0, 0);
    bf16x8 a = x.v;
    f32x4 c[4];
    #pragma unroll
    for (int tl = 0; tl < 4; ++tl) c[tl] = f32x4{0.f,0.f,0.f,0.f};
    #pragma unroll
    for (int tl = 0; tl < 4; ++tl)
      c[tl] = __builtin_amdgcn_mfma_f32_16x16x32_bf16(a, wf[tl], c[tl], 0, 0, 0);
    #pragma unroll
    for (int tl = 0; tl < 4; ++tl){
      #pragma unroll
      for (int rr = 0; rr < 4; ++rr){
        float v = c[tl][rr];
        float pp = __shfl_xor(v, 1);
        if (!(m & 1))
          E1[(size_t)(base + q * 4 + rr) * 32 + (tl * 16 + m) / 2] = packbf2(v, pp);
      }
    }
  }
}

// =============== per step: C12[node] = [h@W1a | h@W1b] bf16 ===============
__global__ __launch_bounds__(256, 4) void k_pre(const unsigned* __restrict__ h_bf,
                                                const unsigned short* __restrict__ W1Tp,
                                                unsigned* __restrict__ C12)
{
  const int t = threadIdx.x, lane = t & 63, wv = t >> 6;
  const int m = lane & 15, q = lane >> 4;
  bf16x8 wa[4][2], wb[4][2];
  #pragma unroll
  for (int tl = 0; tl < 4; ++tl)
    #pragma unroll
    for (int ks = 0; ks < 2; ++ks){
      wa[tl][ks] = ldfrag_g((const unsigned*)(W1Tp + (tl * 16 + m) * 168 + ks * 32 + q * 8));
      wb[tl][ks] = ldfrag_g((const unsigned*)(W1Tp + (tl * 16 + m) * 168 + 64 + ks * 32 + q * 8));
    }
  for (int wt = blockIdx.x * 4 + wv; wt < GTILES; wt += PGRID * 4){
    const int n0 = wt * 16;
    bf16x8 aH[2];
    #pragma unroll
    for (int ks = 0; ks < 2; ++ks)
      aH[ks] = ldfrag_g(h_bf + (size_t)(n0 + m) * 32 + ks * 16 + q * 4);
    f32x4 ca[4], cb[4];
    #pragma unroll
    for (int tl = 0; tl < 4; ++tl){ ca[tl] = f32x4{0.f,0.f,0.f,0.f}; cb[tl] = ca[tl]; }
    #pragma unroll
    for (int ks = 0; ks < 2; ++ks)
      #pragma unroll
      for (int tl = 0; tl < 4; ++tl){
        ca[tl] = __builtin_amdgcn_mfma_f32_16x16x32_bf16(aH[ks], wa[tl][ks], ca[tl], 0, 0, 0);
        cb[tl] = __builtin_amdgcn_mfma_f32_16x16x32_bf16(aH[ks], wb[tl][ks], cb[tl], 0, 0, 0);
      }
    #pragma unroll
    for (int tl = 0; tl < 4; ++tl){
      #pragma unroll
      for (int rr = 0; rr < 4; ++rr){
        const int node = n0 + q * 4 + rr;
        float va = ca[tl][rr], vb = cb[tl][rr];
        float pa = __shfl_xor(va, 1), pb = __shfl_xor(vb, 1);
        if (!(m & 1)){
          C12[(size_t)node * 64 + (tl * 16 + m) / 2]      = packbf2(va, pa);
          C12[(size_t)node * 64 + 32 + (tl * 16 + m) / 2] = packbf2(vb, pb);
        }
      }
    }
  }
}

// =============== embed: h + h_bf ===============
__global__ __launch_bounds__(256) void k_embed(const float* __restrict__ x,
                                               const float* __restrict__ We,
                                               const float* __restrict__ be,
                                               float* __restrict__ h,
                                               unsigned* __restrict__ h_bf)
{
  const int t = threadIdx.x;
  const int j = t & 63, nd = t >> 6;
  const int node = blockIdx.x * 4 + nd;
  const float* xr = x + (size_t)node * AD;
  float acc = be[j];
  #pragma unroll 8
  for (int k = 0; k < AD; ++k)
    acc += xr[k] * We[k * HD + j];
  h[(size_t)node * HD + j] = acc;
  float p = __shfl_down(acc, 1);
  if (!(j & 1)) h_bf[(size_t)node * 32 + (j >> 1)] = packbf2(acc, p);
}

// =============== NEW edge kernel: no LDS, 8 MFMAs/tile ===============
__global__ __launch_bounds__(256, 4) void k_edge(const unsigned* __restrict__ C12,
                                                 const unsigned* __restrict__ E1,
                                                 const int* __restrict__ src_s,
                                                 const int* __restrict__ dst_s,
                                                 const unsigned* __restrict__ W2Tp32,
                                                 const float* __restrict__ b2,
                                                 float* __restrict__ agg)
{
  const int t = threadIdx.x;
  const int lane = t & 63, wv = t >> 6;
  const int m = lane & 15, q = lane >> 4;

  bf16x8 w2f[4][2];
  #pragma unroll
  for (int tl = 0; tl < 4; ++tl)
    #pragma unroll
    for (int ks = 0; ks < 2; ++ks)
      w2f[tl][ks] = ldfrag_g(W2Tp32 + (tl * 16 + m) * 36 + ks * 16 + q * 4);

  float b2v[4];
  #pragma unroll
  for (int tl = 0; tl < 4; ++tl) b2v[tl] = b2[tl * 16 + m];

  const int xcd = blockIdx.x & 7, bi = blockIdx.x >> 3;
  const int wend = (xcd + 1) * TPX;
  const int wstep = (EGRID / 8) * 4;
  int wt = xcd * TPX + bi * 4 + wv;

  int scur = src_s[wt * 16 + m];
  int dcur = dst_s[wt * 16 + m];

  while (wt < wend){
    const int wn = wt + wstep;
    const bool hasn = (wn < wend);
    int sn = 0, dn = 0;
    if (hasn){ sn = src_s[wn * 16 + m]; dn = dst_s[wn * 16 + m]; }

    // gather operands (C1[src], C2[dst], E1 stream)
    const unsigned* c1p = C12 + (size_t)scur * 64;
    const unsigned* c2p = C12 + (size_t)dcur * 64 + 32;
    const unsigned* e1p = E1 + (size_t)(wt * 16 + m) * 32;
    uint4 c1a = *(const uint4*)(c1p + q * 4);
    uint4 c1b = *(const uint4*)(c1p + 16 + q * 4);
    uint4 c2a = *(const uint4*)(c2p + q * 4);
    uint4 c2b = *(const uint4*)(c2p + 16 + q * 4);
    uint4 e1a = *(const uint4*)(e1p + q * 4);
    uint4 e1b = *(const uint4*)(e1p + 16 + q * 4);

    // hidden = relu(C1+C2+E1) -> bf16 A-frags
    bf16x8 af0 = srp4(c1a, c2a, e1a);
    bf16x8 af1 = srp4(c1b, c2b, e1b);

    // GEMM2: out = hidden @ W2
    f32x4 o0 = {0.f,0.f,0.f,0.f}, o1 = o0, o2 = o0, o3 = o0;
    o0 = __builtin_amdgcn_mfma_f32_16x16x32_bf16(af0, w2f[0][0], o0, 0, 0, 0);
    o1 = __builtin_amdgcn_mfma_f32_16x16x32_bf16(af0, w2f[1][0], o1, 0, 0, 0);
    o2 = __builtin_amdgcn_mfma_f32_16x16x32_bf16(af0, w2f[2][0], o2, 0, 0, 0);
    o3 = __builtin_amdgcn_mfma_f32_16x16x32_bf16(af0, w2f[3][0], o3, 0, 0, 0);
    o0 = __builtin_amdgcn_mfma_f32_16x16x32_bf16(af1, w2f[0][1], o0, 0, 0, 0);
    o1 = __builtin_amdgcn_mfma_f32_16x16x32_bf16(af1, w2f[1][1], o1, 0, 0, 0);
    o2 = __builtin_amdgcn_mfma_f32_16x16x32_bf16(af1, w2f[2][1], o2, 0, 0, 0);
    o3 = __builtin_amdgcn_mfma_f32_16x16x32_bf16(af1, w2f[3][1], o3, 0, 0, 0);

    // segment reduce from C-frags (row=edge q*4+rr, col=tl*16+m)
    int prev = __shfl_up(dcur, 1);
    bool isStart = (m == 0) || (dcur != prev);
    unsigned long long bal = __ballot(isStart);
    unsigned bs = (unsigned)bal & 0xFFFFu;
    int nr = __popc(bs);
    unsigned rem = bs & (bs - 1);
    int lo = 0;
    for (int r = 0; r < nr; ++r){
      int hi = rem ? (__ffs(rem) - 1) : 16;
      rem &= rem - 1;
      float s0 = 0.f, s1 = 0.f, s2 = 0.f, s3 = 0.f;
      #pragma unroll
      for (int rr = 0; rr < 4; ++rr){
        int row = q * 4 + rr;
        bool in = (row >= lo) && (row < hi);
        s0 += in ? o0[rr] : 0.f;
        s1 += in ? o1[rr] : 0.f;
        s2 += in ? o2[rr] : 0.f;
        s3 += in ? o3[rr] : 0.f;
      }
      s0 += __shfl_xor(s0, 16); s0 += __shfl_xor(s0, 32);
      s1 += __shfl_xor(s1, 16); s1 += __shfl_xor(s1, 32);
      s2 += __shfl_xor(s2, 16); s2 += __shfl_xor(s2, 32);
      s3 += __shfl_xor(s3, 16); s3 += __shfl_xor(s3, 32);
      int d = __shfl(dcur, lo);
      float cntf = (float)(hi - lo);
      if (q == 0){
        float v0 = s0 + cntf * b2v[0];
        float v1 = s1 + cntf * b2v[1];
        float v2 = s2 + cntf * b2v[2];
        float v3 = s3 + cntf * b2v[3];
        float* dp = &agg[(size_t)d * HD + m];
        if (r == 0 || r == nr - 1){
          atomicAdd(dp +  0, v0); atomicAdd(dp + 16, v1);
          atomicAdd(dp + 32, v2); atomicAdd(dp + 48, v3);
        } else {
          dp[ 0] = v0; dp[16] = v1; dp[32] = v2; dp[48] = v3;
        }
      }
      lo = hi;
    }

    wt = wn; scur = sn; dcur = dn;
  }
}

// =============== fallback edge kernel (round-6 proven path) ===============
__global__ __launch_bounds__(256, 3) void k_edge_fb(const unsigned* __restrict__ h_bf,
                                                    const int* __restrict__ src_s,
                                                    const int* __restrict__ dst_s,
                                                    const unsigned* __restrict__ eattr_bf,
                                                    const unsigned short* __restrict__ W1Tp,
                                                    const float* __restrict__ b1,
                                                    const unsigned* __restrict__ W2Tp32,
                                                    const float* __restrict__ b2,
                                                    float* __restrict__ agg)
{
  __shared__ __align__(16) unsigned short sW1T[64 * 168];
  __shared__ __align__(16) unsigned short sHid[4][16 * 72];

  const int t = threadIdx.x;
  {
    const uint4* srcp = (const uint4*)W1Tp;
    uint4* dstp = (uint4*)sW1T;
    for (int i = t; i < 64 * 168 * 2 / 16; i += 256) dstp[i] = srcp[i];
  }
  __syncthreads();

  const int lane = t & 63, wv = t >> 6;
  const int m = lane & 15, q = lane >> 4;

  bf16x8 w2f[4][2];
  #pragma unroll
  for (int tl = 0; tl < 4; ++tl)
    #pragma unroll
    for (int ks = 0; ks < 2; ++ks)
      w2f[tl][ks] = ldfrag_g(W2Tp32 + (tl * 16 + m) * 36 + ks * 16 + q * 4);

  float b1v[4], b2v[4];
  #pragma unroll
  for (int tl = 0; tl < 4; ++tl){ b1v[tl] = b1[tl * 16 + m]; b2v[tl] = b2[tl * 16 + m]; }

  unsigned short* sHidW = sHid[wv];

  const int xcd = blockIdx.x & 7, bi = blockIdx.x >> 3;
  const int wend = (xcd + 1) * TPX;
  const int wstep = (EGRID_FB / 8) * 4;
  int wt = xcd * TPX + bi * 4 + wv;

  int scur = src_s[wt * 16 + m];
  int dcur = dst_s[wt * 16 + m];
  bf16x8 afc[5];
  {
    const unsigned* hs = h_bf + (size_t)scur * 32;
    const unsigned* hd = h_bf + (size_t)dcur * 32;
    afc[0] = ldfrag_g(hs + q * 4);
    afc[1] = ldfrag_g(hs + 16 + q * 4);
    afc[2] = ldfrag_g(hd + q * 4);
    afc[3] = ldfrag_g(hd + 16 + q * 4);
    if (q < 2) afc[4] = ldfrag_g(eattr_bf + (size_t)(wt * 16 + m) * 8 + q * 4);
    else { U4B x; x.u = make_uint4(0,0,0,0); afc[4] = x.v; }
  }

  while (wt < wend){
    const int wn = wt + wstep;
    const bool hasn = (wn < wend);
    int sn = 0, dn = 0;
    if (hasn){ sn = src_s[wn * 16 + m]; dn = dst_s[wn * 16 + m]; }

    f32x4 a0 = {0.f,0.f,0.f,0.f}, a1 = a0, a2 = a0, a3 = a0;
    #pragma unroll
    for (int ks = 0; ks < 5; ++ks){
      bf16x8 bb0 = *(const bf16x8*)&sW1T[( 0 + m) * 168 + ks * 32 + q * 8];
      bf16x8 bb1 = *(const bf16x8*)&sW1T[(16 + m) * 168 + ks * 32 + q * 8];
      bf16x8 bb2 = *(const bf16x8*)&sW1T[(32 + m) * 168 + ks * 32 + q * 8];
      bf16x8 bb3 = *(const bf16x8*)&sW1T[(48 + m) * 168 + ks * 32 + q * 8];
      a0 = __builtin_amdgcn_mfma_f32_16x16x32_bf16(afc[ks], bb0, a0, 0, 0, 0);
      a1 = __builtin_amdgcn_mfma_f32_16x16x32_bf16(afc[ks], bb1, a1, 0, 0, 0);
      a2 = __builtin_amdgcn_mfma_f32_16x16x32_bf16(afc[ks], bb2, a2, 0, 0, 0);
      a3 = __builtin_amdgcn_mfma_f32_16x16x32_bf16(afc[ks], bb3, a3, 0, 0, 0);
    }
    {
      f32x4 accs[4] = {a0, a1, a2, a3};
      #pragma unroll
      for (int tl = 0; tl < 4; ++tl)
        #pragma unroll
        for (int r = 0; r < 4; ++r)
          sHidW[(q * 4 + r) * 72 + tl * 16 + m] = f2bf(fmaxf(accs[tl][r] + b1v[tl], 0.f));
    }

    bf16x8 afn[5];
    if (hasn){
      const unsigned* hs = h_bf + (size_t)sn * 32;
      const unsigned* hd = h_bf + (size_t)dn * 32;
      afn[0] = ldfrag_g(hs + q * 4);
      afn[1] = ldfrag_g(hs + 16 + q * 4);
      afn[2] = ldfrag_g(hd + q * 4);
      afn[3] = ldfrag_g(hd + 16 + q * 4);
      if (q < 2) afn[4] = ldfrag_g(eattr_bf + (size_t)(wn * 16 + m) * 8 + q * 4);
      else { U4B x; x.u = make_uint4(0,0,0,0); afn[4] = x.v; }
    }

    f32x4 o0 = {0.f,0.f,0.f,0.f}, o1 = o0, o2 = o0, o3 = o0;
    #pragma unroll
    for (int ks = 0; ks < 2; ++ks){
      bf16x8 av = *(const bf16x8*)&sHidW[m * 72 + ks * 32 + q * 8];
      o0 = __builtin_amdgcn_mfma_f32_16x16x32_bf16(av, w2f[0][ks], o0, 0, 0, 0);
      o1 = __builtin_amdgcn_mfma_f32_16x16x32_bf16(av, w2f[1][ks], o1, 0, 0, 0);
      o2 = __builtin_amdgcn_mfma_f32_16x16x32_bf16(av, w2f[2][ks], o2, 0, 0, 0);
      o3 = __builtin_amdgcn_mfma_f32_16x16x32_bf16(av, w2f[3][ks], o3, 0, 0, 0);
    }

    int prev = __shfl_up(dcur, 1);
    bool isStart = (m == 0) || (dcur != prev);
    unsigned long long bal = __ballot(isStart);
    unsigned bs = (unsigned)bal & 0xFFFFu;
    int nr = __popc(bs);
    unsigned rem = bs & (bs - 1);
    int lo = 0;
    for (int r = 0; r < nr; ++r){
      int hi = rem ? (__ffs(rem) - 1) : 16;
      rem &= rem - 1;
      float s0 = 0.f, s1 = 0.f, s2 = 0.f, s3 = 0.f;
      #pragma unroll
      for (int rr = 0; rr < 4; ++rr){
        int row = q * 4 + rr;
        bool in = (row >= lo) && (row < hi);
        s0 += in ? o0[rr] : 0.f;
        s1 += in ? o1[rr] : 0.f;
        s2 += in ? o2[rr] : 0.f;
        s3 += in ? o3[rr] : 0.f;
      }
      s0 += __shfl_xor(s0, 16); s0 += __shfl_xor(s0, 32);
      s1 += __shfl_xor(s1, 16); s1 += __shfl_xor(s1, 32);
      s2 += __shfl_xor(s2, 16); s2 += __shfl_xor(s2, 32);
      s3 += __shfl_xor(s3, 16); s3 += __shfl_xor(s3, 32);
      int d = __shfl(dcur, lo);
      float cntf = (float)(hi - lo);
      if (q == 0){
        float v0 = s0 + cntf * b2v[0];
        float v1 = s1 + cntf * b2v[1];
        float v2 = s2 + cntf * b2v[2];
        float v3 = s3 + cntf * b2v[3];
        float* dp = &agg[(size_t)d * HD + m];
        if (r == 0 || r == nr - 1){
          atomicAdd(dp +  0, v0); atomicAdd(dp + 16, v1);
          atomicAdd(dp + 32, v2); atomicAdd(dp + 48, v3);
        } else {
          dp[ 0] = v0; dp[16] = v1; dp[32] = v2; dp[48] = v3;
        }
      }
      lo = hi;
    }

    wt = wn; scur = sn; dcur = dn;
    #pragma unroll
    for (int i = 0; i < 5; ++i) afc[i] = afn[i];
  }
}

// =============== GRU via MFMA (no agg LDS stage) ===============
__global__ __launch_bounds__(256) void k_gru(const float* __restrict__ agg,
                                             float* __restrict__ h,
                                             unsigned* __restrict__ h_bf,
                                             const unsigned short* __restrict__ Wgru,
                                             const float* __restrict__ bih,
                                             const float* __restrict__ bhh)
{
  __shared__ __align__(16) unsigned short sWg[384 * 64];   // 48 KB

  const int t = threadIdx.x;
  {
    const uint4* srcp = (const uint4*)Wgru;
    uint4* dstp = (uint4*)sWg;
    for (int i = t; i < 384 * 64 * 2 / 16; i += 256) dstp[i] = srcp[i];
  }
  __syncthreads();

  const int lane = t & 63, wv = t >> 6;
  const int m = lane & 15, q = lane >> 4;

  float bi_r[4], bi_z[4], bi_n[4], bh_r[4], bh_z[4], bh_n[4];
  #pragma unroll
  for (int tl = 0; tl < 4; ++tl){
    bi_r[tl] = bih[tl * 16 + m];  bi_z[tl] = bih[64 + tl * 16 + m];  bi_n[tl] = bih[128 + tl * 16 + m];
    bh_r[tl] = bhh[tl * 16 + m];  bh_z[tl] = bhh[64 + tl * 16 + m];  bh_n[tl] = bhh[128 + tl * 16 + m];
  }

  for (int wt = blockIdx.x * 4 + wv; wt < GTILES; wt += GGRID * 4){
    const int n0 = wt * 16;

    bf16x8 aA[2], aH[2];
    #pragma unroll
    for (int ks = 0; ks < 2; ++ks){
      const float* ap = agg + (size_t)(n0 + m) * 64 + ks * 32 + q * 8;
      float4 v0 = *(const float4*)ap;
      float4 v1 = *(const float4*)(ap + 4);
      U4B x;
      x.u.x = packbf2(v0.x, v0.y); x.u.y = packbf2(v0.z, v0.w);
      x.u.z = packbf2(v1.x, v1.y); x.u.w = packbf2(v1.z, v1.w);
      aA[ks] = x.v;
      aH[ks] = ldfrag_g(h_bf + (size_t)(n0 + m) * 32 + ks * 16 + q * 4);
    }

    f32x4 ci[12], ch[12];
    #pragma unroll
    for (int tl = 0; tl < 12; ++tl){ ci[tl] = f32x4{0.f,0.f,0.f,0.f}; ch[tl] = ci[tl]; }
    #pragma unroll
    for (int ks = 0; ks < 2; ++ks){
      #pragma unroll
      for (int tl = 0; tl < 12; ++tl){
        bf16x8 bi = *(const bf16x8*)&sWg[((ks * 4 + q) * 384 + tl * 16 + m) * 8];
        ci[tl] = __builtin_amdgcn_mfma_f32_16x16x32_bf16(aA[ks], bi, ci[tl], 0, 0, 0);
        bf16x8 bh = *(const bf16x8*)&sWg[((ks * 4 + q) * 384 + 192 + tl * 16 + m) * 8];
        ch[tl] = __builtin_amdgcn_mfma_f32_16x16x32_bf16(aH[ks], bh, ch[tl], 0, 0, 0);
      }
    }

    #pragma unroll
    for (int tl = 0; tl < 4; ++tl){
      #pragma unroll
      for (int rr = 0; rr < 4; ++rr){
        const int node = n0 + q * 4 + rr;
        float ir = ci[tl][rr]     + bi_r[tl], hr = ch[tl][rr]     + bh_r[tl];
        float iz = ci[4 + tl][rr] + bi_z[tl], hz = ch[4 + tl][rr] + bh_z[tl];
        float in_ = ci[8 + tl][rr] + bi_n[tl], hn = ch[8 + tl][rr] + bh_n[tl];
        float rg = 1.f / (1.f + __expf(-(ir + hr)));
        float zg = 1.f / (1.f + __expf(-(iz + hz)));
        float ng = tanhf(in_ + rg * hn);
        float hold = h[(size_t)node * HD + tl * 16 + m];
        float hnew = (1.f - zg) * ng + zg * hold;
        h[(size_t)node * HD + tl * 16 + m] = hnew;
        float pp = __shfl_xor(hnew, 1);
        if (!(m & 1))
          h_bf[(size_t)node * 32 + tl * 8 + (m >> 1)] = packbf2(hnew, pp);
      }
    }
  }
}

// =============== pool ===============
__global__ __launch_bounds__(256) void k_pool(const float* __restrict__ h,
                                              const int* __restrict__ batch,
                                              float* __restrict__ gsum,
                                              float* __restrict__ cnt)
{
  const int t = threadIdx.x;
  const int j = t & 63, r = t >> 6;
  const int n0 = blockIdx.x * 64 + r * 16;
  float acc = 0.f, c = 0.f;
  int cur = -1;
  for (int i = 0; i < 16; ++i){
    int n = n0 + i;
    if (n >= NN) break;
    int g = batch[n];
    if (g != cur){
      if (cur >= 0){
        atomicAdd(&gsum[cur * HD + j], acc);
        if (j == 0) atomicAdd(&cnt[cur], c);
      }
      cur = g; acc = 0.f; c = 0.f;
    }
    acc += h[(size_t)n * HD + j];
    c += 1.f;
  }
  if (cur >= 0){
    atomicAdd(&gsum[cur * HD + j], acc);
    if (j == 0) atomicAdd(&cnt[cur], c);
  }
}

// =============== head ===============
__global__ __launch_bounds__(64) void k_head(const float* __restrict__ gsum,
                                             const float* __restrict__ cnt,
                                             const float* __restrict__ W1,
                                             const float* __restrict__ b1,
                                             const float* __restrict__ W2,
                                             const float* __restrict__ b2,
                                             float* __restrict__ out)
{
  __shared__ float gv[128];
  const int g = blockIdx.x, j = threadIdx.x;
  float s = gsum[g * HD + j];
  float c = cnt[g];
  gv[j] = s;
  gv[64 + j] = s / fmaxf(c, 1.f);
  __syncthreads();
  float acc = b1[j];
  #pragma unroll 8
  for (int k = 0; k < 128; ++k)
    acc += gv[k] * W1[k * HD + j];
  acc = fmaxf(acc, 0.f);
  float v = acc * W2[j];
  #pragma unroll
  for (int off = 32; off; off >>= 1) v += __shfl_down(v, off, 64);
  if (j == 0) out[g] = v + b2[0];
}

extern "C" void kernel_launch(void* const* d_in, const int* in_sizes, int n_in,
                              void* d_out, int out_size, void* d_ws, size_t ws_size,
                              hipStream_t stream)
{
  (void)in_sizes; (void)n_in; (void)out_size;
  const float* x     = (const float*)d_in[0];
  const int*   eidx  = (const int*)d_in[1];
  const float* eattr = (const float*)d_in[2];
  const int*   batch = (const int*)d_in[3];
  const float* We    = (const float*)d_in[4];
  const float* be    = (const float*)d_in[5];
  const float* Wm1   = (const float*)d_in[6];
  const float* bm1   = (const float*)d_in[7];
  const float* Wm2   = (const float*)d_in[8];
  const float* bm2   = (const float*)d_in[9];
  const float* Wih   = (const float*)d_in[10];
  const float* bih   = (const float*)d_in[11];
  const float* Whh   = (const float*)d_in[12];
  const float* bhh   = (const float*)d_in[13];
  const float* Wh1   = (const float*)d_in[14];
  const float* bh1   = (const float*)d_in[15];
  const float* Wh2   = (const float*)d_in[16];
  const float* bh2   = (const float*)d_in[17];

  char* w0 = (char*)d_ws;
  char* w = w0;
  float* h     = (float*)w;                      w += (size_t)NN * HD * 4;
  unsigned* h_bf = (unsigned*)w;                 w += (size_t)NN * 32 * 4;
  float* agg   = (float*)w;                      w += (size_t)NN * HD * 4;
  int*   deg   = (int*)w;                        w += (size_t)NN * 4;
  int*   cur   = (int*)w;                        w += (size_t)NN * 4;
  int*   src_s = (int*)w;                        w += (size_t)NE * 4;
  int*   dst_s = (int*)w;                        w += (size_t)NE * 4;
  unsigned* eattr_bf = (unsigned*)w;             w += (size_t)NE * 8 * 4;
  int*   bsum  = (int*)w;                        w += 64 * 4;
  int*   bpre  = (int*)w;                        w += 64 * 4;
  unsigned short* W1Tp = (unsigned short*)w;     w += 64 * 168 * 2;
  unsigned short* W2Tp = (unsigned short*)w;     w += 64 * 72 * 2;
  unsigned short* Wgru = (unsigned short*)w;     w += 384 * 64 * 2;
  unsigned short* W1cTp = (unsigned short*)w;    w += 64 * 32 * 2;
  float* gsum  = (float*)w;                      w += (size_t)NG * HD * 4;
  float* cnt   = (float*)w;                      w += (size_t)NG * 4;
  unsigned* C12 = (unsigned*)w;                  w += (size_t)NN * 64 * 4;
  unsigned* E1  = (unsigned*)w;                  w += (size_t)NE * 32 * 4;
  const bool full = ((size_t)(w - w0) <= ws_size);

  const int nscanb = (NN + 1023) / 1024;

  k_prep<<<164, 256, 0, stream>>>(Wm1, Wm2, Wih, Whh, bm1, W1Tp, W2Tp, Wgru, W1cTp);
  hipMemsetAsync(deg, 0, (size_t)NN * 4, stream);
  k_hist<<<(NE + 255) / 256, 256, 0, stream>>>(eidx, deg);
  k_scan1<<<nscanb, 1024, 0, stream>>>(deg, cur, bsum);
  k_scan2<<<1, 64, 0, stream>>>(bsum, bpre);
  k_scan3<<<nscanb, 1024, 0, stream>>>(cur, bpre);
  k_scatter<<<(NE + 255) / 256, 256, 0, stream>>>(eidx, eattr, cur, src_s, dst_s, eattr_bf);
  if (full)
    k_eprep<<<1024, 256, 0, stream>>>(eattr_bf, (const unsigned*)W1cTp, E1);

  k_embed<<<NN / 4, 256, 0, stream>>>(x, We, be, h, h_bf);
  for (int s = 0; s < 3; ++s){
    hipMemsetAsync(agg, 0, (size_t)NN * HD * 4, stream);
    if (full){
      k_pre<<<PGRID, 256, 0, stream>>>(h_bf, W1Tp, C12);
      k_edge<<<EGRID, 256, 0, stream>>>(C12, E1, src_s, dst_s,
                                        (const unsigned*)W2Tp, bm2, agg);
    } else {
      k_edge_fb<<<EGRID_FB, 256, 0, stream>>>(h_bf, src_s, dst_s, eattr_bf, W1Tp, bm1,
                                              (const unsigned*)W2Tp, bm2, agg);
    }
    k_gru<<<GGRID, 256, 0, stream>>>(agg, h, h_bf, Wgru, bih, bhh);
  }
  hipMemsetAsync(gsum, 0, (size_t)(NG * HD + NG) * 4, stream);
  k_pool<<<(NN + 63) / 64, 256, 0, stream>>>(h, batch, gsum, cnt);
  k_head<<<NG, 64, 0, stream>>>(gsum, cnt, Wh1, bh1, Wh2, bh2, (float*)d_out);
}